// Round 2
// baseline (4232.377 us; speedup 1.0000x reference)
//
#include <hip/hip_runtime.h>
#include <math.h>

// Problem constants: B=4, L=2048, D=1024, H=4, dk=dv=256, CHUNK=32, NCHUNK=64
// All data fp32. Workspace budget: 6 x 32MB slots + 5MB smalls ~= 197 MiB.

// ---------------------------------------------------------------------------
// Tiled fp32 GEMM: C[M,N] = A[M,K] @ B[K,N], row-major.
// BM=128, BN=64, BK=16, 256 threads, 8x4 micro-tile per thread.
// EPI 0: none.
// EPI 2: gelu( x + bias[c] + sum_{j<12} extA[r,j]*extB[j*N+c] )  (exact gelu)
// ---------------------------------------------------------------------------
template<int EPI>
__global__ __launch_bounds__(256) void gemm_f32(const float* __restrict__ A,
    const float* __restrict__ Bm, const float* __restrict__ bias,
    const float* __restrict__ extA, const float* __restrict__ extB,
    float* __restrict__ Cm, int M, int N, int K)
{
    __shared__ float As[16 * 128];
    __shared__ float Bs[16 * 64];
    __shared__ float bns[128][12];
    __shared__ float extBs[12][64];
    const int row0 = blockIdx.y * 128;
    const int col0 = blockIdx.x * 64;
    const int tid = threadIdx.x;
    const int tx = tid & 15, ty = tid >> 4;

    if (EPI == 2) {
        for (int e = tid; e < 128 * 12; e += 256)
            bns[e / 12][e % 12] = extA[(long)(row0 + e / 12) * 12 + e % 12];
        for (int e = tid; e < 12 * 64; e += 256)
            extBs[e >> 6][e & 63] = extB[(long)(e >> 6) * N + col0 + (e & 63)];
    }

    float acc[8][4];
    #pragma unroll
    for (int i = 0; i < 8; ++i)
        #pragma unroll
        for (int j = 0; j < 4; ++j) acc[i][j] = 0.f;

    for (int k0 = 0; k0 < K; k0 += 16) {
        {   // A tile 128x16 -> As[kk][r]
            const int kk = (tid & 3) * 4;
            const int rbase = tid >> 2;
            #pragma unroll
            for (int rep = 0; rep < 2; ++rep) {
                const int r = rep * 64 + rbase;
                const long gr = (long)(row0 + r) * K;
                #pragma unroll
                for (int i = 0; i < 4; ++i) {
                    const int gk = k0 + kk + i;
                    As[(kk + i) * 128 + r] = (gk < K) ? A[gr + gk] : 0.f;
                }
            }
        }
        {   // B tile 16x64 -> Bs[kk][c]
            const int kk = tid >> 4;
            const int c = (tid & 15) * 4;
            const int gk = k0 + kk;
            #pragma unroll
            for (int i = 0; i < 4; ++i)
                Bs[kk * 64 + c + i] = (gk < K) ? Bm[(long)gk * N + col0 + c + i] : 0.f;
        }
        __syncthreads();
        #pragma unroll
        for (int kk = 0; kk < 16; ++kk) {
            float a[8], b[4];
            #pragma unroll
            for (int i = 0; i < 8; ++i) a[i] = As[kk * 128 + ty * 8 + i];
            #pragma unroll
            for (int j = 0; j < 4; ++j) b[j] = Bs[kk * 64 + tx * 4 + j];
            #pragma unroll
            for (int i = 0; i < 8; ++i)
                #pragma unroll
                for (int j = 0; j < 4; ++j) acc[i][j] += a[i] * b[j];
        }
        __syncthreads();
    }
    #pragma unroll
    for (int i = 0; i < 8; ++i) {
        const long r = row0 + ty * 8 + i;
        #pragma unroll
        for (int j = 0; j < 4; ++j) {
            const int c = col0 + tx * 4 + j;
            float vv = acc[i][j];
            if (EPI == 2) {
                vv += bias[c];
                #pragma unroll
                for (int j2 = 0; j2 < 12; ++j2)
                    vv += bns[ty * 8 + i][j2] * extBs[j2][tx * 4 + j];
                vv = 0.5f * vv * (1.f + erff(vv * 0.70710678118654752f));
            }
            Cm[r * N + c] = vv;
        }
    }
}

// ---------------------------------------------------------------------------
// Small-N GEMM (one block per row). MODE 0: sigmoid epilogue (beta).
// MODE 1: +bias then per-head softmax over triples (fusion gate weights).
// ---------------------------------------------------------------------------
template<int NOUT, int MODE>
__global__ __launch_bounds__(256) void gemm_smallN(const float* __restrict__ A,
    const float* __restrict__ Bm, const float* __restrict__ bias,
    float* __restrict__ Cm, int K)
{
    __shared__ float part[4][NOUT];
    __shared__ float sm[NOUT];
    const int m = blockIdx.x, tid = threadIdx.x;
    const float* ar = A + (long)m * K;
    float acc[NOUT];
    #pragma unroll
    for (int j = 0; j < NOUT; ++j) acc[j] = 0.f;
    for (int k = tid; k < K; k += 256) {
        const float a = ar[k];
        #pragma unroll
        for (int j = 0; j < NOUT; ++j) acc[j] += a * Bm[(long)k * NOUT + j];
    }
    #pragma unroll
    for (int j = 0; j < NOUT; ++j)
        for (int off = 32; off > 0; off >>= 1) acc[j] += __shfl_down(acc[j], off);
    const int wid = tid >> 6, lane = tid & 63;
    if (lane == 0) {
        #pragma unroll
        for (int j = 0; j < NOUT; ++j) part[wid][j] = acc[j];
    }
    __syncthreads();
    if (tid < NOUT) {
        float s = part[0][tid] + part[1][tid] + part[2][tid] + part[3][tid];
        if (MODE == 0) {
            Cm[(long)m * NOUT + tid] = 1.f / (1.f + expf(-s));
        } else {
            sm[tid] = s + bias[tid];
        }
    }
    if (MODE == 1) {
        __syncthreads();
        if (tid < NOUT) {
            const int hh = tid / 3, r = tid - hh * 3;
            const float a0 = sm[hh * 3], a1 = sm[hh * 3 + 1], a2 = sm[hh * 3 + 2];
            const float mx = fmaxf(a0, fmaxf(a1, a2));
            const float e0 = expf(a0 - mx), e1 = expf(a1 - mx), e2 = expf(a2 - mx);
            const float mine = (r == 0) ? e0 : ((r == 1) ? e1 : e2);
            Cm[(long)m * NOUT + tid] = mine / (e0 + e1 + e2);
        }
    }
}

// ---------------------------------------------------------------------------
// Depthwise causal conv (k=4) + SiLU. x,y: (B,L,1024). w: (1024,4).
// ---------------------------------------------------------------------------
__global__ __launch_bounds__(256) void conv4_silu(const float* __restrict__ x,
    const float* __restrict__ wc, float* __restrict__ y)
{
    const long idx = (long)blockIdx.x * 256 + threadIdx.x;   // B*L*1024
    const int c = (int)(idx & 1023);
    const long bl = idx >> 10;
    const int l = (int)(bl & 2047);
    const long b = bl >> 11;
    const float* xp = x + b * 2048 * 1024 + c;
    const float* wp = wc + c * 4;
    float s = 0.f;
    #pragma unroll
    for (int t = 0; t < 4; ++t) {
        const int ll = l - 3 + t;
        if (ll >= 0) s += xp[(long)ll * 1024] * wp[t];
    }
    y[idx] = s / (1.f + expf(-s));
}

// ---------------------------------------------------------------------------
// Row-wise l2 normalize (rows of 256), in place. One wave per row.
// ---------------------------------------------------------------------------
__global__ __launch_bounds__(256) void l2norm_rows(float* __restrict__ x, long rows)
{
    const long wid = ((long)blockIdx.x * 256 + threadIdx.x) >> 6;
    const int lane = threadIdx.x & 63;
    if (wid >= rows) return;
    float* r = x + wid * 256;
    float4 xv = *(float4*)(r + lane * 4);
    float ss = xv.x * xv.x + xv.y * xv.y + xv.z * xv.z + xv.w * xv.w;
    for (int off = 32; off > 0; off >>= 1) ss += __shfl_down(ss, off);
    ss = __shfl(ss, 0);
    const float inv = rsqrtf(ss + 1e-6f);
    xv.x *= inv; xv.y *= inv; xv.z *= inv; xv.w *= inv;
    *(float4*)(r + lane * 4) = xv;
}

// ---------------------------------------------------------------------------
// Chunk prep: per chunk (b,h,n):
//   M = -(kb @ kn^T) strictly-lower, R = (I-M)^-1 via nilpotent doubling,
//   u = R @ (v*beta), w = R @ kb, aloc = (qn @ kn^T) * incl_lower.
// 256 threads, grid = B*H*64 = 1024 blocks. LDS = 74 KB (legal on gfx950).
// ---------------------------------------------------------------------------
__global__ __launch_bounds__(256) void chunk_prep(
    const float* __restrict__ qn, const float* __restrict__ kn,
    const float* __restrict__ v, const float* __restrict__ beta,
    float* __restrict__ u, float* __restrict__ wv, float* __restrict__ aloc)
{
    __shared__ float kb_s[32 * 256];   // kb row-major
    __shared__ float bufB[32 * 256];   // knT (dd*32+c), later vb row-major
    __shared__ float Ms[32 * 33];
    __shared__ float Rs[32 * 33];
    __shared__ float bet[32];
    const int blk = blockIdx.x;
    const int n = blk & 63;
    const int bh = blk >> 6;
    const int h = bh & 3;
    const int b = bh >> 2;
    const int tid = threadIdx.x;
    const long lbase = (long)b * 2048 + n * 32;

    if (tid < 32) bet[tid] = beta[(lbase + tid) * 4 + h];
    __syncthreads();
    for (int e = tid; e < 8192; e += 256) {
        const int c = e >> 8, dd = e & 255;
        const float kv = kn[(lbase + c) * 1024 + h * 256 + dd];
        bufB[dd * 32 + c] = kv;               // knT
        kb_s[c * 256 + dd] = kv * bet[c];     // kb
    }
    __syncthreads();

    const int j = tid & 31, i0 = tid >> 5;   // i = i0 + 8*ii
    {   // M = -(kb @ kn^T) strictly lower; R = I + M
        float m4[4] = {0.f, 0.f, 0.f, 0.f};
        for (int dd = 0; dd < 256; ++dd) {
            const float kt = bufB[dd * 32 + j];
            #pragma unroll
            for (int ii = 0; ii < 4; ++ii) m4[ii] += kb_s[(i0 + 8 * ii) * 256 + dd] * kt;
        }
        #pragma unroll
        for (int ii = 0; ii < 4; ++ii) {
            const int i = i0 + 8 * ii;
            const float mv = (i > j) ? -m4[ii] : 0.f;
            Ms[i * 33 + j] = mv;
            Rs[i * 33 + j] = mv + ((i == j) ? 1.f : 0.f);
        }
    }
    {   // aloc = (qn @ kn^T) * incl_lower
        float a4[4] = {0.f, 0.f, 0.f, 0.f};
        for (int dd = 0; dd < 256; ++dd) {
            const float kt = bufB[dd * 32 + j];
            #pragma unroll
            for (int ii = 0; ii < 4; ++ii)
                a4[ii] += qn[(lbase + (i0 + 8 * ii)) * 1024 + h * 256 + dd] * kt;
        }
        #pragma unroll
        for (int ii = 0; ii < 4; ++ii) {
            const int i = i0 + 8 * ii;
            aloc[(long)blk * 1024 + i * 32 + j] = (i >= j) ? a4[ii] : 0.f;
        }
    }
    __syncthreads();
    // R = (I+M)(I+M^2)(I+M^4)(I+M^8)(I+M^16)  (M^32 = 0)
    for (int it = 0; it < 4; ++it) {
        float p4[4] = {0.f, 0.f, 0.f, 0.f};
        for (int kk = 0; kk < 32; ++kk) {
            const float pb = Ms[kk * 33 + j];
            #pragma unroll
            for (int ii = 0; ii < 4; ++ii) p4[ii] += Ms[(i0 + 8 * ii) * 33 + kk] * pb;
        }
        __syncthreads();
        #pragma unroll
        for (int ii = 0; ii < 4; ++ii) Ms[(i0 + 8 * ii) * 33 + j] = p4[ii];
        __syncthreads();
        float r4[4] = {0.f, 0.f, 0.f, 0.f};
        for (int kk = 0; kk < 32; ++kk) {
            const float pb = Ms[kk * 33 + j];
            #pragma unroll
            for (int ii = 0; ii < 4; ++ii) r4[ii] += Rs[(i0 + 8 * ii) * 33 + kk] * pb;
        }
        __syncthreads();
        #pragma unroll
        for (int ii = 0; ii < 4; ++ii) Rs[(i0 + 8 * ii) * 33 + j] += r4[ii];
        __syncthreads();
    }
    // vb = v*beta into bufB (knT dead)
    for (int e = tid; e < 8192; e += 256) {
        const int c = e >> 8, dd = e & 255;
        bufB[c * 256 + dd] = v[(lbase + c) * 1024 + h * 256 + dd] * bet[c];
    }
    __syncthreads();
    {   // u = R @ vb,  w = R @ kb  (thread = dd column)
        const int dd = tid;
        float accU[32], accW[32];
        #pragma unroll
        for (int r = 0; r < 32; ++r) { accU[r] = 0.f; accW[r] = 0.f; }
        for (int kk = 0; kk < 32; ++kk) {
            const float vv = bufB[kk * 256 + dd];
            const float bb = kb_s[kk * 256 + dd];
            #pragma unroll
            for (int r = 0; r < 32; ++r) {
                const float rr = Rs[r * 33 + kk];
                accU[r] += rr * vv;
                accW[r] += rr * bb;
            }
        }
        const long base = (long)blk * 32;
        #pragma unroll
        for (int r = 0; r < 32; ++r) {
            u [(base + r) * 256 + dd] = accU[r];
            wv[(base + r) * 256 + dd] = accW[r];
        }
    }
}

// ---------------------------------------------------------------------------
// Sequential chunk scan. Grid = 16 (b,h) x 16 dv-slices = 256 blocks, 512 thr.
// S slice (256 x 16) in LDS. Per chunk:
//   u' = u - w@S ; o = qn@S + aloc@u' ; S += kn^T @ u'
// ---------------------------------------------------------------------------
__global__ __launch_bounds__(512) void delta_scan(
    const float* __restrict__ qn, const float* __restrict__ kn,
    const float* __restrict__ u, const float* __restrict__ wv,
    const float* __restrict__ aloc, float* __restrict__ dt)
{
    __shared__ float S[256 * 17];
    __shared__ float Us[32 * 17];
    __shared__ float Xs[32 * 260];
    __shared__ float Al[32 * 33];
    const int blk = blockIdx.x;
    const int sl = blk & 15;
    const int bh = blk >> 4;
    const int h = bh & 3;
    const int b = bh >> 2;
    const int v0 = sl * 16;
    const int tid = threadIdx.x;
    const int vv = tid & 15, cc = tid >> 4;   // cc in 0..31

    for (int i = tid; i < 256 * 17; i += 512) S[i] = 0.f;

    for (int n = 0; n < 64; ++n) {
        const long lbase = (long)b * 2048 + n * 32;
        const long ubase = (long)(bh * 64 + n) * 32;
        for (int e = tid; e < 8192; e += 512) {
            const int c = e >> 8, dd = e & 255;
            Xs[c * 260 + dd] = wv[(ubase + c) * 256 + dd];
        }
        for (int e = tid; e < 1024; e += 512)
            Al[(e >> 5) * 33 + (e & 31)] = aloc[(long)(bh * 64 + n) * 1024 + e];
        __syncthreads();
        float s1 = 0.f;
        #pragma unroll 4
        for (int dd = 0; dd < 256; ++dd) s1 += Xs[cc * 260 + dd] * S[dd * 17 + vv];
        const float up = u[(ubase + cc) * 256 + v0 + vv] - s1;
        __syncthreads();
        Us[cc * 17 + vv] = up;
        for (int e = tid; e < 8192; e += 512) {
            const int c = e >> 8, dd = e & 255;
            Xs[c * 260 + dd] = qn[(lbase + c) * 1024 + h * 256 + dd];
        }
        __syncthreads();
        float s2 = 0.f;
        #pragma unroll 4
        for (int dd = 0; dd < 256; ++dd) s2 += Xs[cc * 260 + dd] * S[dd * 17 + vv];
        float s3 = 0.f;
        #pragma unroll
        for (int jj = 0; jj < 32; ++jj) s3 += Al[cc * 33 + jj] * Us[jj * 17 + vv];
        dt[(lbase + cc) * 1024 + h * 256 + v0 + vv] = s2 + s3;
        __syncthreads();
        for (int e = tid; e < 8192; e += 512) {
            const int c = e >> 8, dd = e & 255;
            Xs[c * 260 + dd] = kn[(lbase + c) * 1024 + h * 256 + dd];
        }
        __syncthreads();
        {
            float acc[8];
            #pragma unroll
            for (int r = 0; r < 8; ++r) acc[r] = 0.f;
            for (int c2 = 0; c2 < 32; ++c2) {
                const float uu = Us[c2 * 17 + vv];
                #pragma unroll
                for (int r = 0; r < 8; ++r) acc[r] += Xs[c2 * 260 + cc * 8 + r] * uu;
            }
            #pragma unroll
            for (int r = 0; r < 8; ++r) S[(cc * 8 + r) * 17 + vv] += acc[r];
        }
        __syncthreads();
    }
}

// ---------------------------------------------------------------------------
// Multiscale causal depthwise conv (k=3,15,31), torch-faithful layout.
// Output y: (B, L, H, 768): cat = h*768+j, scale = cat>>10, channel = cat&1023.
// ---------------------------------------------------------------------------
__global__ __launch_bounds__(256) void ms_conv(const float* __restrict__ v,
    const float* __restrict__ w3, const float* __restrict__ w15,
    const float* __restrict__ w31, float* __restrict__ y)
{
    const long idx = (long)blockIdx.x * 256 + threadIdx.x;   // B*L*3072
    const int jj = (int)(idx % 768);
    const long t = idx / 768;
    const int h = (int)(t & 3);
    const long bl = t >> 2;
    const int l = (int)(bl & 2047);
    const long b = bl >> 11;
    const int cat = h * 768 + jj;
    const int sc = cat >> 10;
    const int c = cat & 1023;
    const float* xp = v + b * 2048 * 1024 + c;
    float s = 0.f;
    if (sc == 0) {
        const float* wp = w3 + c * 3;
        #pragma unroll
        for (int t2 = 0; t2 < 3; ++t2) {
            const int ll = l - 2 + t2;
            if (ll >= 0) s += xp[(long)ll * 1024] * wp[t2];
        }
    } else if (sc == 1) {
        const float* wp = w15 + c * 15;
        #pragma unroll
        for (int t2 = 0; t2 < 15; ++t2) {
            const int ll = l - 14 + t2;
            if (ll >= 0) s += xp[(long)ll * 1024] * wp[t2];
        }
    } else {
        const float* wp = w31 + c * 31;
        #pragma unroll
        for (int t2 = 0; t2 < 31; ++t2) {
            const int ll = l - 30 + t2;
            if (ll >= 0) s += xp[(long)ll * 1024] * wp[t2];
        }
    }
    y[idx] = s;
}

// ---------------------------------------------------------------------------
// bn features: bn[bl,12] = [mean|ms| (4 heads) | mean|dt| | mean|v|].
// One block per (b,l); wave = head.
// ---------------------------------------------------------------------------
__global__ __launch_bounds__(256) void build_bn(const float* __restrict__ ms,
    const float* __restrict__ dt, const float* __restrict__ v,
    float* __restrict__ bn)
{
    const int bl = blockIdx.x, tid = threadIdx.x;
    const long rb = (long)bl * 1024;
    const int wid = tid >> 6, lane = tid & 63;
    const long base = rb + wid * 256 + lane * 4;
    float* g = bn + (long)bl * 12;
    float4 a;
    float s;

    a = *(const float4*)(ms + base);
    s = fabsf(a.x) + fabsf(a.y) + fabsf(a.z) + fabsf(a.w);
    for (int off = 32; off > 0; off >>= 1) s += __shfl_down(s, off);
    if (lane == 0) g[wid] = s * (1.f / 256.f);

    a = *(const float4*)(dt + base);
    s = fabsf(a.x) + fabsf(a.y) + fabsf(a.z) + fabsf(a.w);
    for (int off = 32; off > 0; off >>= 1) s += __shfl_down(s, off);
    if (lane == 0) g[4 + wid] = s * (1.f / 256.f);

    a = *(const float4*)(v + base);
    s = fabsf(a.x) + fabsf(a.y) + fabsf(a.z) + fabsf(a.w);
    for (int off = 32; off > 0; off >>= 1) s += __shfl_down(s, off);
    if (lane == 0) g[8 + wid] = s * (1.f / 256.f);
}

// ---------------------------------------------------------------------------
// Blend three branches with gate weights + per-head RMSNorm * o_norm_w.
// ---------------------------------------------------------------------------
__global__ __launch_bounds__(256) void blend_rms(const float* __restrict__ ms,
    const float* __restrict__ dt, const float* __restrict__ v,
    const float* __restrict__ wts, const float* __restrict__ onw,
    float* __restrict__ o)
{
    const int bl = blockIdx.x, tid = threadIdx.x;
    const int wid = tid >> 6, lane = tid & 63;
    const long base = (long)bl * 1024 + wid * 256 + lane * 4;
    const float* wr = wts + (long)bl * 12 + wid * 3;
    const float w0 = wr[0], w1 = wr[1], w2 = wr[2];
    const float4 m = *(const float4*)(ms + base);
    const float4 d = *(const float4*)(dt + base);
    const float4 x = *(const float4*)(v + base);
    float4 ov;
    ov.x = w0 * m.x + w1 * d.x + w2 * x.x;
    ov.y = w0 * m.y + w1 * d.y + w2 * x.y;
    ov.z = w0 * m.z + w1 * d.z + w2 * x.z;
    ov.w = w0 * m.w + w1 * d.w + w2 * x.w;
    float ss = ov.x * ov.x + ov.y * ov.y + ov.z * ov.z + ov.w * ov.w;
    for (int off = 32; off > 0; off >>= 1) ss += __shfl_down(ss, off);
    ss = __shfl(ss, 0);
    const float inv = rsqrtf(ss * (1.f / 256.f) + 1e-5f);
    const float4 nw = *(const float4*)(onw + lane * 4);
    ov.x *= inv * nw.x; ov.y *= inv * nw.y; ov.z *= inv * nw.z; ov.w *= inv * nw.w;
    *(float4*)(o + base) = ov;
}

// ---------------------------------------------------------------------------
extern "C" void kernel_launch(void* const* d_in, const int* in_sizes, int n_in,
                              void* d_out, int out_size, void* d_ws, size_t ws_size,
                              hipStream_t stream)
{
    (void)in_sizes; (void)n_in; (void)out_size; (void)ws_size;
    const float* hid   = (const float*)d_in[0];
    const float* Wq    = (const float*)d_in[1];
    const float* Wk    = (const float*)d_in[2];
    const float* Wv    = (const float*)d_in[3];
    const float* Wb    = (const float*)d_in[4];
    const float* cq    = (const float*)d_in[5];
    const float* ck    = (const float*)d_in[6];
    const float* cv    = (const float*)d_in[7];
    const float* w3    = (const float*)d_in[8];
    const float* w15   = (const float*)d_in[9];
    const float* w31   = (const float*)d_in[10];
    const float* kmix  = (const float*)d_in[11];
    const float* cmix  = (const float*)d_in[12];
    const float* fw1   = (const float*)d_in[13];
    const float* fb1   = (const float*)d_in[14];
    const float* fw2   = (const float*)d_in[15];
    const float* fb2   = (const float*)d_in[16];
    const float* onw   = (const float*)d_in[17];
    const float* Wo    = (const float*)d_in[18];
    float* out = (float*)d_out;

    // ---- 6-slot liveness-scheduled workspace (peak ~197 MiB) ----
    const long SZ = 8192L * 1024;
    float* ws = (float*)d_ws;
    float* s0 = ws;              // qlin -> u  -> yms[0] -> msout
    float* s1 = ws + 1 * SZ;     // klin -> wv -> yms[1] -> hdn[0]
    float* s2 = ws + 2 * SZ;     // q          -> yms[2] -> hdn[1]
    float* s3 = ws + 3 * SZ;     // k  -> mix  -> ofin
    float* s4 = ws + 4 * SZ;     // v (long-lived)
    float* s5 = ws + 5 * SZ;     // vlin -> dt (long-lived)
    float* beta = ws + 6 * SZ;               // 32768
    float* alc  = beta + 32768;              // 1048576
    float* bnf  = alc + 1048576;             // 98304
    float* wts  = bnf + 98304;               // 98304

    float* qlin = s0; float* klin = s1; float* vlin = s5;
    float* q = s2; float* k = s3; float* v = s4;
    float* u = s0; float* wv = s1;
    float* dt = s5;
    float* yms = s0;          // 3*SZ (slots 0,1,2)
    float* mix = s3;
    float* msout = s0;
    float* hdn = s1;          // 2*SZ (slots 1,2)
    float* ofin = s3;

    const dim3 T256(256);
    // 1. projections
    gemm_f32<0><<<dim3(16, 64), T256, 0, stream>>>(hid, Wq, nullptr, nullptr, nullptr, qlin, 8192, 1024, 1024);
    gemm_f32<0><<<dim3(16, 64), T256, 0, stream>>>(hid, Wk, nullptr, nullptr, nullptr, klin, 8192, 1024, 1024);
    gemm_f32<0><<<dim3(16, 64), T256, 0, stream>>>(hid, Wv, nullptr, nullptr, nullptr, vlin, 8192, 1024, 1024);
    gemm_smallN<4, 0><<<8192, T256, 0, stream>>>(hid, Wb, nullptr, beta, 1024);
    // 2. short conv + silu
    conv4_silu<<<32768, T256, 0, stream>>>(qlin, cq, q);
    conv4_silu<<<32768, T256, 0, stream>>>(klin, ck, k);
    conv4_silu<<<32768, T256, 0, stream>>>(vlin, cv, v);
    // 3. l2 norm q,k (in place)
    l2norm_rows<<<8192, T256, 0, stream>>>(q, 32768);
    l2norm_rows<<<8192, T256, 0, stream>>>(k, 32768);
    // 4. delta-rule chunk prep + sequential scan
    chunk_prep<<<1024, T256, 0, stream>>>(q, k, v, beta, u, wv, alc);
    delta_scan<<<256, dim3(512), 0, stream>>>(q, k, u, wv, alc, dt);
    // 5. multiscale conv branch (q,k,u,wv dead; yms overlays slots 0-2)
    ms_conv<<<98304, T256, 0, stream>>>(v, w3, w15, w31, yms);
    gemm_f32<0><<<dim3(4, 256), T256, 0, stream>>>(yms, kmix, nullptr, nullptr, nullptr, mix, 32768, 256, 768);
    gemm_f32<0><<<dim3(16, 64), T256, 0, stream>>>(mix, cmix, nullptr, nullptr, nullptr, msout, 8192, 1024, 1024);
    // 6. fusion gate: bn features + rank-12 fused GEMM + softmax
    build_bn<<<8192, T256, 0, stream>>>(msout, dt, v, bnf);
    gemm_f32<2><<<dim3(32, 64), T256, 0, stream>>>(hid, fw1, fb1, bnf, fw1 + 1024L * 2048,
                                                   hdn, 8192, 2048, 1024);
    gemm_smallN<12, 1><<<8192, T256, 0, stream>>>(hdn, fw2, fb2, wts, 2048);
    // 7. blend + RMSNorm + output projection
    blend_rms<<<8192, T256, 0, stream>>>(msout, dt, v, wts, onw, ofin);
    gemm_f32<0><<<dim3(16, 64), T256, 0, stream>>>(ofin, Wo, nullptr, nullptr, nullptr, out, 8192, 1024, 1024);
}

// Round 3
// 2091.114 us; speedup vs baseline: 2.0240x; 2.0240x over previous
//
#include <hip/hip_runtime.h>
#include <math.h>

// Problem constants: B=4, L=2048, D=1024, H=4, dk=dv=256, CHUNK=32, NCHUNK=64
// bf16 MFMA for all large GEMMs; delta-rule pipeline unchanged from round 2.

typedef __attribute__((ext_vector_type(8))) __bf16 bf16x8;
typedef __attribute__((ext_vector_type(4))) float f32x4;

__device__ inline ushort f2bf(float f) {
    union { float f; unsigned u; } x; x.f = f;
    unsigned u = x.u;
    u += 0x7fffu + ((u >> 16) & 1u);
    return (ushort)(u >> 16);
}
__device__ inline float bf2f(ushort h) {
    union { unsigned u; float f; } x; x.u = ((unsigned)h) << 16;
    return x.f;
}
__device__ inline float ldf(float v) { return v; }
__device__ inline float ldf(ushort v) { return bf2f(v); }

// ---------------------------------------------------------------------------
// bf16 MFMA GEMM: C[M,N] = A[M,K] @ BT[N,K]^T. 128x128 tile, BK=32, 4 waves.
// EPI 0: f32 out. 1: bf16 out. 3: bias+rank12+gelu, bf16 out.
// M%128==0, N%128==0, K%32==0.
// ---------------------------------------------------------------------------
template<int EPI>
__global__ __launch_bounds__(256) void gemm_mfma(
    const ushort* __restrict__ A, const ushort* __restrict__ BT,
    const float* __restrict__ bias, const float* __restrict__ extA,
    const float* __restrict__ extB, void* __restrict__ Cout,
    int M, int N, int K)
{
    __shared__ ushort As[128 * 32];
    __shared__ ushort Bs[128 * 32];
    __shared__ float bns[(EPI >= 2) ? 128 * 13 : 1];
    __shared__ float exb[(EPI >= 2) ? 12 * 128 : 1];
    const int tid = threadIdx.x;
    const int row0 = blockIdx.y * 128, col0 = blockIdx.x * 128;
    const int lane = tid & 63, wave = tid >> 6;
    const int wr = (wave >> 1) * 64, wc = (wave & 1) * 64;

    if (EPI >= 2) {
        for (int e = tid; e < 128 * 12; e += 256)
            bns[(e / 12) * 13 + (e % 12)] = extA[(long)(row0 + e / 12) * 12 + e % 12];
        for (int e = tid; e < 12 * 128; e += 256)
            exb[e] = extB[(long)(e >> 7) * N + col0 + (e & 127)];
    }

    f32x4 acc[4][4];
    #pragma unroll
    for (int m = 0; m < 4; ++m)
        #pragma unroll
        for (int n = 0; n < 4; ++n) {
            acc[m][n][0] = 0.f; acc[m][n][1] = 0.f;
            acc[m][n][2] = 0.f; acc[m][n][3] = 0.f;
        }

    const int rA = lane & 15;
    const int ko = (lane >> 4) * 8;
    const int srow = tid >> 2;          // 0..63
    const int skk = (tid & 3) * 8;

    for (int k0 = 0; k0 < K; k0 += 32) {
        #pragma unroll
        for (int i = 0; i < 2; ++i) {
            const long ga = (long)(row0 + i * 64 + srow) * K + k0 + skk;
            __builtin_amdgcn_global_load_lds(
                (const __attribute__((address_space(1))) void*)(A + ga),
                (__attribute__((address_space(3))) void*)(As + i * 2048 + wave * 512),
                16, 0, 0);
            const long gb = (long)(col0 + i * 64 + srow) * K + k0 + skk;
            __builtin_amdgcn_global_load_lds(
                (const __attribute__((address_space(1))) void*)(BT + gb),
                (__attribute__((address_space(3))) void*)(Bs + i * 2048 + wave * 512),
                16, 0, 0);
        }
        __syncthreads();
        bf16x8 af[4], bfr[4];
        #pragma unroll
        for (int m = 0; m < 4; ++m)
            af[m] = *(const bf16x8*)(As + (wr + m * 16 + rA) * 32 + ko);
        #pragma unroll
        for (int n = 0; n < 4; ++n)
            bfr[n] = *(const bf16x8*)(Bs + (wc + n * 16 + rA) * 32 + ko);
        #pragma unroll
        for (int m = 0; m < 4; ++m)
            #pragma unroll
            for (int n = 0; n < 4; ++n)
                acc[m][n] = __builtin_amdgcn_mfma_f32_16x16x32_bf16(af[m], bfr[n], acc[m][n], 0, 0, 0);
        __syncthreads();
    }

    const int crow = (lane >> 4) * 4;
    const int ccol = lane & 15;
    #pragma unroll
    for (int m = 0; m < 4; ++m) {
        #pragma unroll
        for (int n = 0; n < 4; ++n) {
            #pragma unroll
            for (int r = 0; r < 4; ++r) {
                const int rl = wr + m * 16 + crow + r;
                const int cl = wc + n * 16 + ccol;
                float vv = acc[m][n][r];
                if (EPI >= 2) {
                    vv += bias[col0 + cl];
                    #pragma unroll
                    for (int j = 0; j < 12; ++j) vv += bns[rl * 13 + j] * exb[j * 128 + cl];
                    vv = 0.5f * vv * (1.f + erff(vv * 0.70710678118654752f));
                }
                const long off = (long)(row0 + rl) * N + col0 + cl;
                if (EPI == 0) ((float*)Cout)[off] = vv;
                else ((ushort*)Cout)[off] = f2bf(vv);
            }
        }
    }
}

// ---------------------------------------------------------------------------
// Transpose + cast to bf16: W[K][N] f32 -> WT[N][K] bf16. K,N % 32 == 0.
// ---------------------------------------------------------------------------
__global__ __launch_bounds__(256) void transpose_cast(const float* __restrict__ W,
    ushort* __restrict__ WT, int K, int N)
{
    __shared__ float t[32][33];
    const int k0 = blockIdx.y * 32, n0 = blockIdx.x * 32;
    const int c = threadIdx.x & 31, r8 = threadIdx.x >> 5;
    #pragma unroll
    for (int rr = 0; rr < 4; ++rr) {
        const int r = r8 + rr * 8;
        t[r][c] = W[(long)(k0 + r) * N + n0 + c];
    }
    __syncthreads();
    #pragma unroll
    for (int rr = 0; rr < 4; ++rr) {
        const int r = r8 + rr * 8;
        WT[(long)(n0 + r) * K + k0 + c] = f2bf(t[c][r]);
    }
}

// Cast fp32 -> bf16, 4 elements per thread.
__global__ __launch_bounds__(256) void cast_bf16(const float* __restrict__ x,
    ushort* __restrict__ y)
{
    const long i = ((long)blockIdx.x * 256 + threadIdx.x) * 4;
    const float4 v = *(const float4*)(x + i);
    ushort4 o;
    o.x = f2bf(v.x); o.y = f2bf(v.y); o.z = f2bf(v.z); o.w = f2bf(v.w);
    *(ushort4*)(y + i) = o;
}

// ---------------------------------------------------------------------------
// Small-N GEMM (one block per row). MODE 0: sigmoid. MODE 1: +bias, softmax/3.
// ---------------------------------------------------------------------------
template<int NOUT, int MODE, typename TA>
__global__ __launch_bounds__(256) void gemm_smallN(const TA* __restrict__ A,
    const float* __restrict__ Bm, const float* __restrict__ bias,
    float* __restrict__ Cm, int K)
{
    __shared__ float part[4][NOUT];
    __shared__ float sm[NOUT];
    const int m = blockIdx.x, tid = threadIdx.x;
    const TA* ar = A + (long)m * K;
    float acc[NOUT];
    #pragma unroll
    for (int j = 0; j < NOUT; ++j) acc[j] = 0.f;
    for (int k = tid; k < K; k += 256) {
        const float a = ldf(ar[k]);
        #pragma unroll
        for (int j = 0; j < NOUT; ++j) acc[j] += a * Bm[(long)k * NOUT + j];
    }
    #pragma unroll
    for (int j = 0; j < NOUT; ++j)
        for (int off = 32; off > 0; off >>= 1) acc[j] += __shfl_down(acc[j], off);
    const int wid = tid >> 6, lane = tid & 63;
    if (lane == 0) {
        #pragma unroll
        for (int j = 0; j < NOUT; ++j) part[wid][j] = acc[j];
    }
    __syncthreads();
    if (tid < NOUT) {
        float s = part[0][tid] + part[1][tid] + part[2][tid] + part[3][tid];
        if (MODE == 0) {
            Cm[(long)m * NOUT + tid] = 1.f / (1.f + expf(-s));
        } else {
            sm[tid] = s + bias[tid];
        }
    }
    if (MODE == 1) {
        __syncthreads();
        if (tid < NOUT) {
            const int hh = tid / 3, r = tid - hh * 3;
            const float a0 = sm[hh * 3], a1 = sm[hh * 3 + 1], a2 = sm[hh * 3 + 2];
            const float mx = fmaxf(a0, fmaxf(a1, a2));
            const float e0 = expf(a0 - mx), e1 = expf(a1 - mx), e2 = expf(a2 - mx);
            const float mine = (r == 0) ? e0 : ((r == 1) ? e1 : e2);
            Cm[(long)m * NOUT + tid] = mine / (e0 + e1 + e2);
        }
    }
}

// ---------------------------------------------------------------------------
// Depthwise causal conv (k=4) + SiLU, fp32 -> fp32.
// ---------------------------------------------------------------------------
__global__ __launch_bounds__(256) void conv4_silu(const float* __restrict__ x,
    const float* __restrict__ wc, float* __restrict__ y)
{
    const long idx = (long)blockIdx.x * 256 + threadIdx.x;
    const int c = (int)(idx & 1023);
    const long bl = idx >> 10;
    const int l = (int)(bl & 2047);
    const long b = bl >> 11;
    const float* xp = x + b * 2048 * 1024 + c;
    const float* wp = wc + c * 4;
    float s = 0.f;
    #pragma unroll
    for (int t = 0; t < 4; ++t) {
        const int ll = l - 3 + t;
        if (ll >= 0) s += xp[(long)ll * 1024] * wp[t];
    }
    y[idx] = s / (1.f + expf(-s));
}

// ---------------------------------------------------------------------------
// l2 normalize rows of 256 (fp32 in), write bf16. One wave per row.
// ---------------------------------------------------------------------------
__global__ __launch_bounds__(256) void l2norm_bf16(const float* __restrict__ x,
    ushort* __restrict__ y)
{
    const long wid = ((long)blockIdx.x * 256 + threadIdx.x) >> 6;
    const int lane = threadIdx.x & 63;
    const float4 xv = *(const float4*)(x + wid * 256 + lane * 4);
    float ss = xv.x * xv.x + xv.y * xv.y + xv.z * xv.z + xv.w * xv.w;
    for (int off = 32; off > 0; off >>= 1) ss += __shfl_down(ss, off);
    ss = __shfl(ss, 0);
    const float inv = rsqrtf(ss + 1e-6f);
    ushort4 o;
    o.x = f2bf(xv.x * inv); o.y = f2bf(xv.y * inv);
    o.z = f2bf(xv.z * inv); o.w = f2bf(xv.w * inv);
    *(ushort4*)(y + wid * 256 + lane * 4) = o;
}

// ---------------------------------------------------------------------------
// Chunk prep (q,k in bf16; fp32 math). Grid = 1024 blocks x 256 thr.
// ---------------------------------------------------------------------------
__global__ __launch_bounds__(256) void chunk_prep(
    const ushort* __restrict__ qn, const ushort* __restrict__ kn,
    const float* __restrict__ v, const float* __restrict__ beta,
    float* __restrict__ u, float* __restrict__ wv, float* __restrict__ aloc)
{
    __shared__ float kb_s[32 * 256];
    __shared__ float bufB[32 * 256];
    __shared__ float Ms[32 * 33];
    __shared__ float Rs[32 * 33];
    __shared__ float bet[32];
    const int blk = blockIdx.x;
    const int n = blk & 63;
    const int bh = blk >> 6;
    const int h = bh & 3;
    const int b = bh >> 2;
    const int tid = threadIdx.x;
    const long lbase = (long)b * 2048 + n * 32;

    if (tid < 32) bet[tid] = beta[(lbase + tid) * 4 + h];
    __syncthreads();
    for (int e = tid; e < 8192; e += 256) {
        const int c = e >> 8, dd = e & 255;
        const float kv = bf2f(kn[(lbase + c) * 1024 + h * 256 + dd]);
        bufB[dd * 32 + c] = kv;
        kb_s[c * 256 + dd] = kv * bet[c];
    }
    __syncthreads();

    const int j = tid & 31, i0 = tid >> 5;
    {
        float m4[4] = {0.f, 0.f, 0.f, 0.f};
        for (int dd = 0; dd < 256; ++dd) {
            const float kt = bufB[dd * 32 + j];
            #pragma unroll
            for (int ii = 0; ii < 4; ++ii) m4[ii] += kb_s[(i0 + 8 * ii) * 256 + dd] * kt;
        }
        #pragma unroll
        for (int ii = 0; ii < 4; ++ii) {
            const int i = i0 + 8 * ii;
            const float mv = (i > j) ? -m4[ii] : 0.f;
            Ms[i * 33 + j] = mv;
            Rs[i * 33 + j] = mv + ((i == j) ? 1.f : 0.f);
        }
    }
    {
        float a4[4] = {0.f, 0.f, 0.f, 0.f};
        for (int dd = 0; dd < 256; ++dd) {
            const float kt = bufB[dd * 32 + j];
            #pragma unroll
            for (int ii = 0; ii < 4; ++ii)
                a4[ii] += bf2f(qn[(lbase + (i0 + 8 * ii)) * 1024 + h * 256 + dd]) * kt;
        }
        #pragma unroll
        for (int ii = 0; ii < 4; ++ii) {
            const int i = i0 + 8 * ii;
            aloc[(long)blk * 1024 + i * 32 + j] = (i >= j) ? a4[ii] : 0.f;
        }
    }
    __syncthreads();
    for (int it = 0; it < 4; ++it) {
        float p4[4] = {0.f, 0.f, 0.f, 0.f};
        for (int kk = 0; kk < 32; ++kk) {
            const float pb = Ms[kk * 33 + j];
            #pragma unroll
            for (int ii = 0; ii < 4; ++ii) p4[ii] += Ms[(i0 + 8 * ii) * 33 + kk] * pb;
        }
        __syncthreads();
        #pragma unroll
        for (int ii = 0; ii < 4; ++ii) Ms[(i0 + 8 * ii) * 33 + j] = p4[ii];
        __syncthreads();
        float r4[4] = {0.f, 0.f, 0.f, 0.f};
        for (int kk = 0; kk < 32; ++kk) {
            const float pb = Ms[kk * 33 + j];
            #pragma unroll
            for (int ii = 0; ii < 4; ++ii) r4[ii] += Rs[(i0 + 8 * ii) * 33 + kk] * pb;
        }
        __syncthreads();
        #pragma unroll
        for (int ii = 0; ii < 4; ++ii) Rs[(i0 + 8 * ii) * 33 + j] += r4[ii];
        __syncthreads();
    }
    for (int e = tid; e < 8192; e += 256) {
        const int c = e >> 8, dd = e & 255;
        bufB[c * 256 + dd] = v[(lbase + c) * 1024 + h * 256 + dd] * bet[c];
    }
    __syncthreads();
    {
        const int dd = tid;
        float accU[32], accW[32];
        #pragma unroll
        for (int r = 0; r < 32; ++r) { accU[r] = 0.f; accW[r] = 0.f; }
        for (int kk = 0; kk < 32; ++kk) {
            const float vv = bufB[kk * 256 + dd];
            const float bb = kb_s[kk * 256 + dd];
            #pragma unroll
            for (int r = 0; r < 32; ++r) {
                const float rr = Rs[r * 33 + kk];
                accU[r] += rr * vv;
                accW[r] += rr * bb;
            }
        }
        const long base = (long)blk * 32;
        #pragma unroll
        for (int r = 0; r < 32; ++r) {
            u [(base + r) * 256 + dd] = accU[r];
            wv[(base + r) * 256 + dd] = accW[r];
        }
    }
}

// ---------------------------------------------------------------------------
// Sequential chunk scan (q,k bf16; u,w fp32). 256 blocks x 512 thr.
// ---------------------------------------------------------------------------
__global__ __launch_bounds__(512) void delta_scan(
    const ushort* __restrict__ qn, const ushort* __restrict__ kn,
    const float* __restrict__ u, const float* __restrict__ wv,
    const float* __restrict__ aloc, float* __restrict__ dt)
{
    __shared__ float S[256 * 17];
    __shared__ float Us[32 * 17];
    __shared__ float Xs[32 * 260];
    __shared__ float Al[32 * 33];
    const int blk = blockIdx.x;
    const int sl = blk & 15;
    const int bh = blk >> 4;
    const int h = bh & 3;
    const int b = bh >> 2;
    const int v0 = sl * 16;
    const int tid = threadIdx.x;
    const int vv = tid & 15, cc = tid >> 4;

    for (int i = tid; i < 256 * 17; i += 512) S[i] = 0.f;

    for (int n = 0; n < 64; ++n) {
        const long lbase = (long)b * 2048 + n * 32;
        const long ubase = (long)(bh * 64 + n) * 32;
        for (int e = tid; e < 8192; e += 512) {
            const int c = e >> 8, dd = e & 255;
            Xs[c * 260 + dd] = wv[(ubase + c) * 256 + dd];
        }
        for (int e = tid; e < 1024; e += 512)
            Al[(e >> 5) * 33 + (e & 31)] = aloc[(long)(bh * 64 + n) * 1024 + e];
        __syncthreads();
        float s1 = 0.f;
        #pragma unroll 4
        for (int dd = 0; dd < 256; ++dd) s1 += Xs[cc * 260 + dd] * S[dd * 17 + vv];
        const float up = u[(ubase + cc) * 256 + v0 + vv] - s1;
        __syncthreads();
        Us[cc * 17 + vv] = up;
        for (int e = tid; e < 8192; e += 512) {
            const int c = e >> 8, dd = e & 255;
            Xs[c * 260 + dd] = bf2f(qn[(lbase + c) * 1024 + h * 256 + dd]);
        }
        __syncthreads();
        float s2 = 0.f;
        #pragma unroll 4
        for (int dd = 0; dd < 256; ++dd) s2 += Xs[cc * 260 + dd] * S[dd * 17 + vv];
        float s3 = 0.f;
        #pragma unroll
        for (int jj = 0; jj < 32; ++jj) s3 += Al[cc * 33 + jj] * Us[jj * 17 + vv];
        dt[(lbase + cc) * 1024 + h * 256 + v0 + vv] = s2 + s3;
        __syncthreads();
        for (int e = tid; e < 8192; e += 512) {
            const int c = e >> 8, dd = e & 255;
            Xs[c * 260 + dd] = bf2f(kn[(lbase + c) * 1024 + h * 256 + dd]);
        }
        __syncthreads();
        {
            float acc[8];
            #pragma unroll
            for (int r = 0; r < 8; ++r) acc[r] = 0.f;
            for (int c2 = 0; c2 < 32; ++c2) {
                const float uu = Us[c2 * 17 + vv];
                #pragma unroll
                for (int r = 0; r < 8; ++r) acc[r] += Xs[c2 * 260 + cc * 8 + r] * uu;
            }
            #pragma unroll
            for (int r = 0; r < 8; ++r) S[(cc * 8 + r) * 17 + vv] += acc[r];
        }
        __syncthreads();
    }
}

// ---------------------------------------------------------------------------
// Multiscale causal depthwise conv -> bf16 out, torch-faithful layout.
// ---------------------------------------------------------------------------
__global__ __launch_bounds__(256) void ms_conv(const float* __restrict__ v,
    const float* __restrict__ w3, const float* __restrict__ w15,
    const float* __restrict__ w31, ushort* __restrict__ y)
{
    const long idx = (long)blockIdx.x * 256 + threadIdx.x;
    const int jj = (int)(idx % 768);
    const long t = idx / 768;
    const int h = (int)(t & 3);
    const long bl = t >> 2;
    const int l = (int)(bl & 2047);
    const long b = bl >> 11;
    const int cat = h * 768 + jj;
    const int sc = cat >> 10;
    const int c = cat & 1023;
    const float* xp = v + b * 2048 * 1024 + c;
    float s = 0.f;
    if (sc == 0) {
        const float* wp = w3 + c * 3;
        #pragma unroll
        for (int t2 = 0; t2 < 3; ++t2) {
            const int ll = l - 2 + t2;
            if (ll >= 0) s += xp[(long)ll * 1024] * wp[t2];
        }
    } else if (sc == 1) {
        const float* wp = w15 + c * 15;
        #pragma unroll
        for (int t2 = 0; t2 < 15; ++t2) {
            const int ll = l - 14 + t2;
            if (ll >= 0) s += xp[(long)ll * 1024] * wp[t2];
        }
    } else {
        const float* wp = w31 + c * 31;
        #pragma unroll
        for (int t2 = 0; t2 < 31; ++t2) {
            const int ll = l - 30 + t2;
            if (ll >= 0) s += xp[(long)ll * 1024] * wp[t2];
        }
    }
    y[idx] = f2bf(s);
}

// ---------------------------------------------------------------------------
// bn features: bn[bl,12] = [mean|ms| | mean|dt| | mean|v|] per head.
// ---------------------------------------------------------------------------
__global__ __launch_bounds__(256) void build_bn(const float* __restrict__ ms,
    const float* __restrict__ dt, const float* __restrict__ v,
    float* __restrict__ bn)
{
    const int bl = blockIdx.x, tid = threadIdx.x;
    const long rb = (long)bl * 1024;
    const int wid = tid >> 6, lane = tid & 63;
    const long base = rb + wid * 256 + lane * 4;
    float* g = bn + (long)bl * 12;
    float4 a;
    float s;
    a = *(const float4*)(ms + base);
    s = fabsf(a.x) + fabsf(a.y) + fabsf(a.z) + fabsf(a.w);
    for (int off = 32; off > 0; off >>= 1) s += __shfl_down(s, off);
    if (lane == 0) g[wid] = s * (1.f / 256.f);
    a = *(const float4*)(dt + base);
    s = fabsf(a.x) + fabsf(a.y) + fabsf(a.z) + fabsf(a.w);
    for (int off = 32; off > 0; off >>= 1) s += __shfl_down(s, off);
    if (lane == 0) g[4 + wid] = s * (1.f / 256.f);
    a = *(const float4*)(v + base);
    s = fabsf(a.x) + fabsf(a.y) + fabsf(a.z) + fabsf(a.w);
    for (int off = 32; off > 0; off >>= 1) s += __shfl_down(s, off);
    if (lane == 0) g[8 + wid] = s * (1.f / 256.f);
}

// ---------------------------------------------------------------------------
// Blend + per-head RMSNorm * o_norm_w -> bf16 out.
// ---------------------------------------------------------------------------
__global__ __launch_bounds__(256) void blend_rms(const float* __restrict__ ms,
    const float* __restrict__ dt, const float* __restrict__ v,
    const float* __restrict__ wts, const float* __restrict__ onw,
    ushort* __restrict__ o)
{
    const int bl = blockIdx.x, tid = threadIdx.x;
    const int wid = tid >> 6, lane = tid & 63;
    const long base = (long)bl * 1024 + wid * 256 + lane * 4;
    const float* wr = wts + (long)bl * 12 + wid * 3;
    const float w0 = wr[0], w1 = wr[1], w2 = wr[2];
    const float4 m = *(const float4*)(ms + base);
    const float4 d = *(const float4*)(dt + base);
    const float4 x = *(const float4*)(v + base);
    float4 ov;
    ov.x = w0 * m.x + w1 * d.x + w2 * x.x;
    ov.y = w0 * m.y + w1 * d.y + w2 * x.y;
    ov.z = w0 * m.z + w1 * d.z + w2 * x.z;
    ov.w = w0 * m.w + w1 * d.w + w2 * x.w;
    float ss = ov.x * ov.x + ov.y * ov.y + ov.z * ov.z + ov.w * ov.w;
    for (int off = 32; off > 0; off >>= 1) ss += __shfl_down(ss, off);
    ss = __shfl(ss, 0);
    const float inv = rsqrtf(ss * (1.f / 256.f) + 1e-5f);
    const float4 nw = *(const float4*)(onw + lane * 4);
    ushort4 ob;
    ob.x = f2bf(ov.x * inv * nw.x); ob.y = f2bf(ov.y * inv * nw.y);
    ob.z = f2bf(ov.z * inv * nw.z); ob.w = f2bf(ov.w * inv * nw.w);
    *(ushort4*)(o + base) = ob;
}

// ---------------------------------------------------------------------------
extern "C" void kernel_launch(void* const* d_in, const int* in_sizes, int n_in,
                              void* d_out, int out_size, void* d_ws, size_t ws_size,
                              hipStream_t stream)
{
    (void)in_sizes; (void)n_in; (void)out_size; (void)ws_size;
    const float* hid   = (const float*)d_in[0];
    const float* Wq    = (const float*)d_in[1];
    const float* Wk    = (const float*)d_in[2];
    const float* Wv    = (const float*)d_in[3];
    const float* Wb    = (const float*)d_in[4];
    const float* cq    = (const float*)d_in[5];
    const float* ck    = (const float*)d_in[6];
    const float* cv    = (const float*)d_in[7];
    const float* w3    = (const float*)d_in[8];
    const float* w15   = (const float*)d_in[9];
    const float* w31   = (const float*)d_in[10];
    const float* kmix  = (const float*)d_in[11];
    const float* cmix  = (const float*)d_in[12];
    const float* fw1   = (const float*)d_in[13];
    const float* fb1   = (const float*)d_in[14];
    const float* fw2   = (const float*)d_in[15];
    const float* fb2   = (const float*)d_in[16];
    const float* onw   = (const float*)d_in[17];
    const float* Wo    = (const float*)d_in[18];
    float* out = (float*)d_out;

    // ---- workspace carve (peak ~196 MiB) ----
    const size_t MiB = 1024 * 1024;
    char* W = (char*)d_ws;
    float*  s0    = (float*)(W);              // qlin -> u -> yms[lo] -> hdn16
    float*  s1    = (float*)(W + 32 * MiB);   // qtmp -> wv -> yms[hi] -> msout
    float*  s2    = (float*)(W + 64 * MiB);   // vlin -> dt
    char*   s3    = W + 96 * MiB;             // q16|k16 -> mix16|ofin16
    float*  s4    = (float*)(W + 128 * MiB);  // v (long-lived)
    ushort* hid16 = (ushort*)(W + 160 * MiB);
    ushort* WqT   = (ushort*)(W + 176 * MiB);
    ushort* WkT   = WqT   + 1024 * 1024;
    ushort* WvT   = WkT   + 1024 * 1024;
    ushort* cmixT = WvT   + 1024 * 1024;
    ushort* WoT   = cmixT + 1024 * 1024;
    ushort* fw1T  = WoT   + 1024 * 1024;      // [2048][1024]
    ushort* kmixT = fw1T  + 2048 * 1024;      // [256][768]
    float*  beta  = (float*)(W + 191 * MiB);
    float*  alc   = beta + 32768;
    float*  bnf   = alc + 1048576;
    float*  wts   = bnf + 98304;

    ushort* q16    = (ushort*)s3;
    ushort* k16    = (ushort*)(s3 + 16 * MiB);
    ushort* mix16  = q16;
    ushort* ofin16 = k16;
    ushort* yms16  = (ushort*)s0;             // 50 MiB spans s0+s1
    ushort* hdn16  = (ushort*)s0;
    float*  qlin = s0; float* qtmp = s1;
    float*  u = s0; float* wvb = s1;
    float*  dt = s2; float* v = s4; float* msout = s1;

    const dim3 T256(256);
    // 0. casts / weight transposes
    cast_bf16<<<8192, T256, 0, stream>>>(hid, hid16);
    transpose_cast<<<dim3(32, 32), T256, 0, stream>>>(Wq, WqT, 1024, 1024);
    transpose_cast<<<dim3(32, 32), T256, 0, stream>>>(Wk, WkT, 1024, 1024);
    transpose_cast<<<dim3(32, 32), T256, 0, stream>>>(Wv, WvT, 1024, 1024);
    transpose_cast<<<dim3(32, 32), T256, 0, stream>>>(cmix, cmixT, 1024, 1024);
    transpose_cast<<<dim3(32, 32), T256, 0, stream>>>(Wo, WoT, 1024, 1024);
    transpose_cast<<<dim3(64, 32), T256, 0, stream>>>(fw1, fw1T, 1024, 2048);
    transpose_cast<<<dim3(8, 24), T256, 0, stream>>>(kmix, kmixT, 768, 256);
    // 1. q pipeline
    gemm_mfma<0><<<dim3(8, 64), T256, 0, stream>>>(hid16, WqT, nullptr, nullptr, nullptr, qlin, 8192, 1024, 1024);
    conv4_silu<<<32768, T256, 0, stream>>>(qlin, cq, qtmp);
    l2norm_bf16<<<8192, T256, 0, stream>>>(qtmp, q16);
    // 2. k pipeline
    gemm_mfma<0><<<dim3(8, 64), T256, 0, stream>>>(hid16, WkT, nullptr, nullptr, nullptr, qlin, 8192, 1024, 1024);
    conv4_silu<<<32768, T256, 0, stream>>>(qlin, ck, qtmp);
    l2norm_bf16<<<8192, T256, 0, stream>>>(qtmp, k16);
    // 3. v pipeline
    gemm_mfma<0><<<dim3(8, 64), T256, 0, stream>>>(hid16, WvT, nullptr, nullptr, nullptr, qlin, 8192, 1024, 1024);
    conv4_silu<<<32768, T256, 0, stream>>>(qlin, cv, v);
    // 4. beta
    gemm_smallN<4, 0><<<8192, T256, 0, stream>>>(hid, Wb, nullptr, beta, 1024);
    // 5. delta rule
    chunk_prep<<<1024, T256, 0, stream>>>(q16, k16, v, beta, u, wvb, alc);
    delta_scan<<<256, dim3(512), 0, stream>>>(q16, k16, u, wvb, alc, dt);
    // 6. multiscale conv branch
    ms_conv<<<98304, T256, 0, stream>>>(v, w3, w15, w31, yms16);
    gemm_mfma<1><<<dim3(2, 256), T256, 0, stream>>>(yms16, kmixT, nullptr, nullptr, nullptr, mix16, 32768, 256, 768);
    gemm_mfma<0><<<dim3(8, 64), T256, 0, stream>>>(mix16, cmixT, nullptr, nullptr, nullptr, msout, 8192, 1024, 1024);
    // 7. fusion gate
    build_bn<<<8192, T256, 0, stream>>>(msout, dt, v, bnf);
    gemm_mfma<3><<<dim3(16, 64), T256, 0, stream>>>(hid16, fw1T, fb1, bnf, fw1 + 1024L * 2048, hdn16, 8192, 2048, 1024);
    gemm_smallN<12, 1><<<8192, T256, 0, stream>>>(hdn16, fw2, fb2, wts, 2048);
    // 8. blend + output projection
    blend_rms<<<8192, T256, 0, stream>>>(msout, dt, v, wts, onw, ofin16);
    gemm_mfma<0><<<dim3(8, 64), T256, 0, stream>>>(ofin16, WoT, nullptr, nullptr, nullptr, out, 8192, 1024, 1024);
}

// Round 4
// 1998.142 us; speedup vs baseline: 2.1182x; 1.0465x over previous
//
#include <hip/hip_runtime.h>
#include <math.h>

// Problem constants: B=4, L=2048, D=1024, H=4, dk=dv=256, CHUNK=32, NCHUNK=64
// bf16 MFMA for all large GEMMs AND the delta-rule scan.

typedef __attribute__((ext_vector_type(8))) __bf16 bf16x8;
typedef __attribute__((ext_vector_type(4))) float f32x4;

__device__ inline ushort f2bf(float f) {
    union { float f; unsigned u; } x; x.f = f;
    unsigned u = x.u;
    u += 0x7fffu + ((u >> 16) & 1u);
    return (ushort)(u >> 16);
}
__device__ inline float bf2f(ushort h) {
    union { unsigned u; float f; } x; x.u = ((unsigned)h) << 16;
    return x.f;
}
__device__ inline float ldf(float v) { return v; }
__device__ inline float ldf(ushort v) { return bf2f(v); }

// ---------------------------------------------------------------------------
// bf16 MFMA GEMM: C[M,N] = A[M,K] @ BT[N,K]^T. 128x128 tile, BK=32, 4 waves.
// EPI 0: f32 out. 1: bf16 out. 3: bias+rank12+gelu, bf16 out.
// ---------------------------------------------------------------------------
template<int EPI>
__global__ __launch_bounds__(256) void gemm_mfma(
    const ushort* __restrict__ A, const ushort* __restrict__ BT,
    const float* __restrict__ bias, const float* __restrict__ extA,
    const float* __restrict__ extB, void* __restrict__ Cout,
    int M, int N, int K)
{
    __shared__ ushort As[128 * 32];
    __shared__ ushort Bs[128 * 32];
    __shared__ float bns[(EPI >= 2) ? 128 * 13 : 1];
    __shared__ float exb[(EPI >= 2) ? 12 * 128 : 1];
    const int tid = threadIdx.x;
    const int row0 = blockIdx.y * 128, col0 = blockIdx.x * 128;
    const int lane = tid & 63, wave = tid >> 6;
    const int wr = (wave >> 1) * 64, wc = (wave & 1) * 64;

    if (EPI >= 2) {
        for (int e = tid; e < 128 * 12; e += 256)
            bns[(e / 12) * 13 + (e % 12)] = extA[(long)(row0 + e / 12) * 12 + e % 12];
        for (int e = tid; e < 12 * 128; e += 256)
            exb[e] = extB[(long)(e >> 7) * N + col0 + (e & 127)];
    }

    f32x4 acc[4][4];
    #pragma unroll
    for (int m = 0; m < 4; ++m)
        #pragma unroll
        for (int n = 0; n < 4; ++n) {
            acc[m][n][0] = 0.f; acc[m][n][1] = 0.f;
            acc[m][n][2] = 0.f; acc[m][n][3] = 0.f;
        }

    const int rA = lane & 15;
    const int ko = (lane >> 4) * 8;
    const int srow = tid >> 2;
    const int skk = (tid & 3) * 8;

    for (int k0 = 0; k0 < K; k0 += 32) {
        #pragma unroll
        for (int i = 0; i < 2; ++i) {
            const long ga = (long)(row0 + i * 64 + srow) * K + k0 + skk;
            __builtin_amdgcn_global_load_lds(
                (const __attribute__((address_space(1))) void*)(A + ga),
                (__attribute__((address_space(3))) void*)(As + i * 2048 + wave * 512),
                16, 0, 0);
            const long gb = (long)(col0 + i * 64 + srow) * K + k0 + skk;
            __builtin_amdgcn_global_load_lds(
                (const __attribute__((address_space(1))) void*)(BT + gb),
                (__attribute__((address_space(3))) void*)(Bs + i * 2048 + wave * 512),
                16, 0, 0);
        }
        __syncthreads();
        bf16x8 af[4], bfr[4];
        #pragma unroll
        for (int m = 0; m < 4; ++m)
            af[m] = *(const bf16x8*)(As + (wr + m * 16 + rA) * 32 + ko);
        #pragma unroll
        for (int n = 0; n < 4; ++n)
            bfr[n] = *(const bf16x8*)(Bs + (wc + n * 16 + rA) * 32 + ko);
        #pragma unroll
        for (int m = 0; m < 4; ++m)
            #pragma unroll
            for (int n = 0; n < 4; ++n)
                acc[m][n] = __builtin_amdgcn_mfma_f32_16x16x32_bf16(af[m], bfr[n], acc[m][n], 0, 0, 0);
        __syncthreads();
    }

    const int crow = (lane >> 4) * 4;
    const int ccol = lane & 15;
    #pragma unroll
    for (int m = 0; m < 4; ++m) {
        #pragma unroll
        for (int n = 0; n < 4; ++n) {
            #pragma unroll
            for (int r = 0; r < 4; ++r) {
                const int rl = wr + m * 16 + crow + r;
                const int cl = wc + n * 16 + ccol;
                float vv = acc[m][n][r];
                if (EPI >= 2) {
                    vv += bias[col0 + cl];
                    #pragma unroll
                    for (int j = 0; j < 12; ++j) vv += bns[rl * 13 + j] * exb[j * 128 + cl];
                    vv = 0.5f * vv * (1.f + erff(vv * 0.70710678118654752f));
                }
                const long off = (long)(row0 + rl) * N + col0 + cl;
                if (EPI == 0) ((float*)Cout)[off] = vv;
                else ((ushort*)Cout)[off] = f2bf(vv);
            }
        }
    }
}

// ---------------------------------------------------------------------------
// Transpose + cast to bf16: W[K][N] f32 -> WT[N][K] bf16.
// ---------------------------------------------------------------------------
__global__ __launch_bounds__(256) void transpose_cast(const float* __restrict__ W,
    ushort* __restrict__ WT, int K, int N)
{
    __shared__ float t[32][33];
    const int k0 = blockIdx.y * 32, n0 = blockIdx.x * 32;
    const int c = threadIdx.x & 31, r8 = threadIdx.x >> 5;
    #pragma unroll
    for (int rr = 0; rr < 4; ++rr) {
        const int r = r8 + rr * 8;
        t[r][c] = W[(long)(k0 + r) * N + n0 + c];
    }
    __syncthreads();
    #pragma unroll
    for (int rr = 0; rr < 4; ++rr) {
        const int r = r8 + rr * 8;
        WT[(long)(n0 + r) * K + k0 + c] = f2bf(t[c][r]);
    }
}

__global__ __launch_bounds__(256) void cast_bf16(const float* __restrict__ x,
    ushort* __restrict__ y)
{
    const long i = ((long)blockIdx.x * 256 + threadIdx.x) * 4;
    const float4 v = *(const float4*)(x + i);
    ushort4 o;
    o.x = f2bf(v.x); o.y = f2bf(v.y); o.z = f2bf(v.z); o.w = f2bf(v.w);
    *(ushort4*)(y + i) = o;
}

// ---------------------------------------------------------------------------
// Small-N GEMM. MODE 0: sigmoid. MODE 1: +bias, per-head softmax over triples.
// ---------------------------------------------------------------------------
template<int NOUT, int MODE, typename TA>
__global__ __launch_bounds__(256) void gemm_smallN(const TA* __restrict__ A,
    const float* __restrict__ Bm, const float* __restrict__ bias,
    float* __restrict__ Cm, int K)
{
    __shared__ float part[4][NOUT];
    __shared__ float sm[NOUT];
    const int m = blockIdx.x, tid = threadIdx.x;
    const TA* ar = A + (long)m * K;
    float acc[NOUT];
    #pragma unroll
    for (int j = 0; j < NOUT; ++j) acc[j] = 0.f;
    for (int k = tid; k < K; k += 256) {
        const float a = ldf(ar[k]);
        #pragma unroll
        for (int j = 0; j < NOUT; ++j) acc[j] += a * Bm[(long)k * NOUT + j];
    }
    #pragma unroll
    for (int j = 0; j < NOUT; ++j)
        for (int off = 32; off > 0; off >>= 1) acc[j] += __shfl_down(acc[j], off);
    const int wid = tid >> 6, lane = tid & 63;
    if (lane == 0) {
        #pragma unroll
        for (int j = 0; j < NOUT; ++j) part[wid][j] = acc[j];
    }
    __syncthreads();
    if (tid < NOUT) {
        float s = part[0][tid] + part[1][tid] + part[2][tid] + part[3][tid];
        if (MODE == 0) {
            Cm[(long)m * NOUT + tid] = 1.f / (1.f + expf(-s));
        } else {
            sm[tid] = s + bias[tid];
        }
    }
    if (MODE == 1) {
        __syncthreads();
        if (tid < NOUT) {
            const int hh = tid / 3, r = tid - hh * 3;
            const float a0 = sm[hh * 3], a1 = sm[hh * 3 + 1], a2 = sm[hh * 3 + 2];
            const float mx = fmaxf(a0, fmaxf(a1, a2));
            const float e0 = expf(a0 - mx), e1 = expf(a1 - mx), e2 = expf(a2 - mx);
            const float mine = (r == 0) ? e0 : ((r == 1) ? e1 : e2);
            Cm[(long)m * NOUT + tid] = mine / (e0 + e1 + e2);
        }
    }
}

// ---------------------------------------------------------------------------
// Depthwise causal conv (k=4) + SiLU, fp32 -> fp32.
// ---------------------------------------------------------------------------
__global__ __launch_bounds__(256) void conv4_silu(const float* __restrict__ x,
    const float* __restrict__ wc, float* __restrict__ y)
{
    const long idx = (long)blockIdx.x * 256 + threadIdx.x;
    const int c = (int)(idx & 1023);
    const long bl = idx >> 10;
    const int l = (int)(bl & 2047);
    const long b = bl >> 11;
    const float* xp = x + b * 2048 * 1024 + c;
    const float* wp = wc + c * 4;
    float s = 0.f;
    #pragma unroll
    for (int t = 0; t < 4; ++t) {
        const int ll = l - 3 + t;
        if (ll >= 0) s += xp[(long)ll * 1024] * wp[t];
    }
    y[idx] = s / (1.f + expf(-s));
}

// ---------------------------------------------------------------------------
// l2 normalize rows of 256 (fp32 in), write bf16.
// ---------------------------------------------------------------------------
__global__ __launch_bounds__(256) void l2norm_bf16(const float* __restrict__ x,
    ushort* __restrict__ y)
{
    const long wid = ((long)blockIdx.x * 256 + threadIdx.x) >> 6;
    const int lane = threadIdx.x & 63;
    const float4 xv = *(const float4*)(x + wid * 256 + lane * 4);
    float ss = xv.x * xv.x + xv.y * xv.y + xv.z * xv.z + xv.w * xv.w;
    for (int off = 32; off > 0; off >>= 1) ss += __shfl_down(ss, off);
    ss = __shfl(ss, 0);
    const float inv = rsqrtf(ss + 1e-6f);
    ushort4 o;
    o.x = f2bf(xv.x * inv); o.y = f2bf(xv.y * inv);
    o.z = f2bf(xv.z * inv); o.w = f2bf(xv.w * inv);
    *(ushort4*)(y + wid * 256 + lane * 4) = o;
}

// ---------------------------------------------------------------------------
// Chunk prep. Outputs: u (f32), w16 [blk][32][256] bf16, kT16 [blk][256][32]
// bf16, al16 [blk][32][32] bf16.
// ---------------------------------------------------------------------------
__global__ __launch_bounds__(256) void chunk_prep(
    const ushort* __restrict__ qn, const ushort* __restrict__ kn,
    const float* __restrict__ v, const float* __restrict__ beta,
    float* __restrict__ u, ushort* __restrict__ w16,
    ushort* __restrict__ kT16, ushort* __restrict__ al16)
{
    __shared__ float kb_s[32 * 256];
    __shared__ float bufB[32 * 256];
    __shared__ float Ms[32 * 33];
    __shared__ float Rs[32 * 33];
    __shared__ float bet[32];
    const int blk = blockIdx.x;
    const int n = blk & 63;
    const int bh = blk >> 6;
    const int h = bh & 3;
    const int b = bh >> 2;
    const int tid = threadIdx.x;
    const long lbase = (long)b * 2048 + n * 32;

    if (tid < 32) bet[tid] = beta[(lbase + tid) * 4 + h];
    __syncthreads();
    for (int e = tid; e < 8192; e += 256) {
        const int c = e >> 8, dd = e & 255;
        const float kv = bf2f(kn[(lbase + c) * 1024 + h * 256 + dd]);
        bufB[dd * 32 + c] = kv;
        kb_s[c * 256 + dd] = kv * bet[c];
    }
    __syncthreads();
    // kT16 out (bufB layout is [dd][c] already)
    for (int e = tid; e < 8192; e += 256)
        kT16[(long)blk * 8192 + e] = f2bf(bufB[e]);

    const int j = tid & 31, i0 = tid >> 5;
    {
        float m4[4] = {0.f, 0.f, 0.f, 0.f};
        for (int dd = 0; dd < 256; ++dd) {
            const float kt = bufB[dd * 32 + j];
            #pragma unroll
            for (int ii = 0; ii < 4; ++ii) m4[ii] += kb_s[(i0 + 8 * ii) * 256 + dd] * kt;
        }
        #pragma unroll
        for (int ii = 0; ii < 4; ++ii) {
            const int i = i0 + 8 * ii;
            const float mv = (i > j) ? -m4[ii] : 0.f;
            Ms[i * 33 + j] = mv;
            Rs[i * 33 + j] = mv + ((i == j) ? 1.f : 0.f);
        }
    }
    {
        float a4[4] = {0.f, 0.f, 0.f, 0.f};
        for (int dd = 0; dd < 256; ++dd) {
            const float kt = bufB[dd * 32 + j];
            #pragma unroll
            for (int ii = 0; ii < 4; ++ii)
                a4[ii] += bf2f(qn[(lbase + (i0 + 8 * ii)) * 1024 + h * 256 + dd]) * kt;
        }
        #pragma unroll
        for (int ii = 0; ii < 4; ++ii) {
            const int i = i0 + 8 * ii;
            al16[(long)blk * 1024 + i * 32 + j] = f2bf((i >= j) ? a4[ii] : 0.f);
        }
    }
    __syncthreads();
    // R = (I+M)(I+M^2)(I+M^4)(I+M^8)(I+M^16)
    for (int it = 0; it < 4; ++it) {
        float p4[4] = {0.f, 0.f, 0.f, 0.f};
        for (int kk = 0; kk < 32; ++kk) {
            const float pb = Ms[kk * 33 + j];
            #pragma unroll
            for (int ii = 0; ii < 4; ++ii) p4[ii] += Ms[(i0 + 8 * ii) * 33 + kk] * pb;
        }
        __syncthreads();
        #pragma unroll
        for (int ii = 0; ii < 4; ++ii) Ms[(i0 + 8 * ii) * 33 + j] = p4[ii];
        __syncthreads();
        float r4[4] = {0.f, 0.f, 0.f, 0.f};
        for (int kk = 0; kk < 32; ++kk) {
            const float pb = Ms[kk * 33 + j];
            #pragma unroll
            for (int ii = 0; ii < 4; ++ii) r4[ii] += Rs[(i0 + 8 * ii) * 33 + kk] * pb;
        }
        __syncthreads();
        #pragma unroll
        for (int ii = 0; ii < 4; ++ii) Rs[(i0 + 8 * ii) * 33 + j] += r4[ii];
        __syncthreads();
    }
    for (int e = tid; e < 8192; e += 256) {
        const int c = e >> 8, dd = e & 255;
        bufB[c * 256 + dd] = v[(lbase + c) * 1024 + h * 256 + dd] * bet[c];
    }
    __syncthreads();
    {
        const int dd = tid;
        float accU[32], accW[32];
        #pragma unroll
        for (int r = 0; r < 32; ++r) { accU[r] = 0.f; accW[r] = 0.f; }
        for (int kk = 0; kk < 32; ++kk) {
            const float vv = bufB[kk * 256 + dd];
            const float bb = kb_s[kk * 256 + dd];
            #pragma unroll
            for (int r = 0; r < 32; ++r) {
                const float rr = Rs[r * 33 + kk];
                accU[r] += rr * vv;
                accW[r] += rr * bb;
            }
        }
        const long base = (long)blk * 32;
        #pragma unroll
        for (int r = 0; r < 32; ++r) {
            u  [(base + r) * 256 + dd] = accU[r];
            w16[(base + r) * 256 + dd] = f2bf(accW[r]);
        }
    }
}

// ---------------------------------------------------------------------------
// MFMA delta scan. 256 blocks x 64 threads (1 wave). Block = (bh, slice):
// bh = blk & 15 (keeps all 16 slices of a (b,h) on one XCD), sl = blk >> 4.
// S-slice (256 x 16) lives in MFMA accumulators; per chunk:
//   u' = u - w@S ; o = q@S + aloc@u' ; S += kT@u'
// S and u' round-trip LDS in bf16 for B-operand fragment layout.
// ---------------------------------------------------------------------------
__global__ __launch_bounds__(64) void delta_scan_mfma(
    const ushort* __restrict__ q16, const ushort* __restrict__ kT16,
    const ushort* __restrict__ w16, const float* __restrict__ u,
    const ushort* __restrict__ al16, float* __restrict__ dt)
{
    __shared__ ushort Sb[16 * 264];   // Sb[col][dd], stride 264
    __shared__ ushort Ub[16 * 40];    // Ub[col][c],  stride 40
    const int blk = blockIdx.x;
    const int bh = blk & 15;
    const int sl = blk >> 4;
    const int h = bh & 3;
    const int b = bh >> 2;
    const int v0 = sl * 16;
    const int lane = threadIdx.x;
    const int col = lane & 15;        // A-row / B-col / C-col index
    const int grp = lane >> 4;        // 0..3

    f32x4 S[16];
    #pragma unroll
    for (int t = 0; t < 16; ++t) { S[t][0] = 0.f; S[t][1] = 0.f; S[t][2] = 0.f; S[t][3] = 0.f; }
    for (int i = lane; i < 16 * 264; i += 64) Sb[i] = 0;
    __syncthreads();

    // per-lane base pointers (advance by constants per chunk)
    const ushort* wp  = w16  + ((long)bh * 64 * 32 + col) * 256 + grp * 8;
    const ushort* qp  = q16  + ((long)b * 2048 + col) * 1024 + h * 256 + grp * 8;
    const ushort* kp  = kT16 + ((long)bh * 64 * 256 + col) * 32 + grp * 8;
    const ushort* ap  = al16 + ((long)bh * 64 * 32 + col) * 32 + grp * 8;
    const float*  upt = u    + ((long)bh * 64 * 32 + grp * 4) * 256 + v0 + col;
    float*        dp  = dt   + ((long)b * 2048 + grp * 4) * 1024 + h * 256 + v0 + col;

    for (int n = 0; n < 64; ++n) {
        // --- read S B-frags (col-major S in Sb)
        bf16x8 sf[8];
        #pragma unroll
        for (int kb = 0; kb < 8; ++kb)
            sf[kb] = *(const bf16x8*)&Sb[col * 264 + kb * 32 + grp * 8];

        // --- u' = u - w@S
        f32x4 up[2];
        #pragma unroll
        for (int rt = 0; rt < 2; ++rt) {
            f32x4 a; a[0] = 0.f; a[1] = 0.f; a[2] = 0.f; a[3] = 0.f;
            #pragma unroll
            for (int kb = 0; kb < 8; ++kb) {
                const bf16x8 wf = *(const bf16x8*)(wp + (long)n * 8192 + rt * 4096 + kb * 32);
                a = __builtin_amdgcn_mfma_f32_16x16x32_bf16(wf, sf[kb], a, 0, 0, 0);
            }
            #pragma unroll
            for (int r = 0; r < 4; ++r)
                up[rt][r] = upt[(long)n * 8192 + rt * 4096 + r * 256] - a[r];
        }
        // --- write u' (bf16, col-major) to Ub
        #pragma unroll
        for (int rt = 0; rt < 2; ++rt) {
            ushort4 p;
            p.x = f2bf(up[rt][0]); p.y = f2bf(up[rt][1]);
            p.z = f2bf(up[rt][2]); p.w = f2bf(up[rt][3]);
            *(ushort4*)&Ub[col * 40 + rt * 16 + grp * 4] = p;
        }
        __syncthreads();
        const bf16x8 uf = *(const bf16x8*)&Ub[col * 40 + grp * 8];

        // --- o = q@S + aloc@u' ; store to dt
        #pragma unroll
        for (int rt = 0; rt < 2; ++rt) {
            f32x4 a; a[0] = 0.f; a[1] = 0.f; a[2] = 0.f; a[3] = 0.f;
            #pragma unroll
            for (int kb = 0; kb < 8; ++kb) {
                const bf16x8 qf = *(const bf16x8*)(qp + (long)n * 32768 + rt * 16384 + kb * 32);
                a = __builtin_amdgcn_mfma_f32_16x16x32_bf16(qf, sf[kb], a, 0, 0, 0);
            }
            const bf16x8 alf = *(const bf16x8*)(ap + (long)n * 1024 + rt * 512);
            a = __builtin_amdgcn_mfma_f32_16x16x32_bf16(alf, uf, a, 0, 0, 0);
            #pragma unroll
            for (int r = 0; r < 4; ++r)
                dp[(long)n * 32768 + rt * 16384 + r * 1024] = a[r];
        }

        // --- S += kT @ u'
        #pragma unroll
        for (int t = 0; t < 16; ++t) {
            const bf16x8 kf = *(const bf16x8*)(kp + (long)n * 8192 + t * 512);
            S[t] = __builtin_amdgcn_mfma_f32_16x16x32_bf16(kf, uf, S[t], 0, 0, 0);
        }

        // --- write S (bf16, col-major) to Sb for next chunk
        __syncthreads();
        #pragma unroll
        for (int t = 0; t < 16; ++t) {
            ushort4 p;
            p.x = f2bf(S[t][0]); p.y = f2bf(S[t][1]);
            p.z = f2bf(S[t][2]); p.w = f2bf(S[t][3]);
            *(ushort4*)&Sb[col * 264 + t * 16 + grp * 4] = p;
        }
        __syncthreads();
    }
}

// ---------------------------------------------------------------------------
// Multiscale causal depthwise conv -> bf16 out, torch-faithful layout.
// ---------------------------------------------------------------------------
__global__ __launch_bounds__(256) void ms_conv(const float* __restrict__ v,
    const float* __restrict__ w3, const float* __restrict__ w15,
    const float* __restrict__ w31, ushort* __restrict__ y)
{
    const long idx = (long)blockIdx.x * 256 + threadIdx.x;
    const int jj = (int)(idx % 768);
    const long t = idx / 768;
    const int h = (int)(t & 3);
    const long bl = t >> 2;
    const int l = (int)(bl & 2047);
    const long b = bl >> 11;
    const int cat = h * 768 + jj;
    const int sc = cat >> 10;
    const int c = cat & 1023;
    const float* xp = v + b * 2048 * 1024 + c;
    float s = 0.f;
    if (sc == 0) {
        const float* wp = w3 + c * 3;
        #pragma unroll
        for (int t2 = 0; t2 < 3; ++t2) {
            const int ll = l - 2 + t2;
            if (ll >= 0) s += xp[(long)ll * 1024] * wp[t2];
        }
    } else if (sc == 1) {
        const float* wp = w15 + c * 15;
        #pragma unroll
        for (int t2 = 0; t2 < 15; ++t2) {
            const int ll = l - 14 + t2;
            if (ll >= 0) s += xp[(long)ll * 1024] * wp[t2];
        }
    } else {
        const float* wp = w31 + c * 31;
        #pragma unroll
        for (int t2 = 0; t2 < 31; ++t2) {
            const int ll = l - 30 + t2;
            if (ll >= 0) s += xp[(long)ll * 1024] * wp[t2];
        }
    }
    y[idx] = f2bf(s);
}

// ---------------------------------------------------------------------------
// bn features: bn[bl,12] = [mean|ms| | mean|dt| | mean|v|] per head.
// ---------------------------------------------------------------------------
__global__ __launch_bounds__(256) void build_bn(const float* __restrict__ ms,
    const float* __restrict__ dt, const float* __restrict__ v,
    float* __restrict__ bn)
{
    const int bl = blockIdx.x, tid = threadIdx.x;
    const long rb = (long)bl * 1024;
    const int wid = tid >> 6, lane = tid & 63;
    const long base = rb + wid * 256 + lane * 4;
    float* g = bn + (long)bl * 12;
    float4 a;
    float s;
    a = *(const float4*)(ms + base);
    s = fabsf(a.x) + fabsf(a.y) + fabsf(a.z) + fabsf(a.w);
    for (int off = 32; off > 0; off >>= 1) s += __shfl_down(s, off);
    if (lane == 0) g[wid] = s * (1.f / 256.f);
    a = *(const float4*)(dt + base);
    s = fabsf(a.x) + fabsf(a.y) + fabsf(a.z) + fabsf(a.w);
    for (int off = 32; off > 0; off >>= 1) s += __shfl_down(s, off);
    if (lane == 0) g[4 + wid] = s * (1.f / 256.f);
    a = *(const float4*)(v + base);
    s = fabsf(a.x) + fabsf(a.y) + fabsf(a.z) + fabsf(a.w);
    for (int off = 32; off > 0; off >>= 1) s += __shfl_down(s, off);
    if (lane == 0) g[8 + wid] = s * (1.f / 256.f);
}

// ---------------------------------------------------------------------------
// Blend + per-head RMSNorm * o_norm_w -> bf16 out.
// ---------------------------------------------------------------------------
__global__ __launch_bounds__(256) void blend_rms(const float* __restrict__ ms,
    const float* __restrict__ dt, const float* __restrict__ v,
    const float* __restrict__ wts, const float* __restrict__ onw,
    ushort* __restrict__ o)
{
    const int bl = blockIdx.x, tid = threadIdx.x;
    const int wid = tid >> 6, lane = tid & 63;
    const long base = (long)bl * 1024 + wid * 256 + lane * 4;
    const float* wr = wts + (long)bl * 12 + wid * 3;
    const float w0 = wr[0], w1 = wr[1], w2 = wr[2];
    const float4 m = *(const float4*)(ms + base);
    const float4 d = *(const float4*)(dt + base);
    const float4 x = *(const float4*)(v + base);
    float4 ov;
    ov.x = w0 * m.x + w1 * d.x + w2 * x.x;
    ov.y = w0 * m.y + w1 * d.y + w2 * x.y;
    ov.z = w0 * m.z + w1 * d.z + w2 * x.z;
    ov.w = w0 * m.w + w1 * d.w + w2 * x.w;
    float ss = ov.x * ov.x + ov.y * ov.y + ov.z * ov.z + ov.w * ov.w;
    for (int off = 32; off > 0; off >>= 1) ss += __shfl_down(ss, off);
    ss = __shfl(ss, 0);
    const float inv = rsqrtf(ss * (1.f / 256.f) + 1e-5f);
    const float4 nw = *(const float4*)(onw + lane * 4);
    ushort4 ob;
    ob.x = f2bf(ov.x * inv * nw.x); ob.y = f2bf(ov.y * inv * nw.y);
    ob.z = f2bf(ov.z * inv * nw.z); ob.w = f2bf(ov.w * inv * nw.w);
    *(ushort4*)(o + base) = ob;
}

// ---------------------------------------------------------------------------
extern "C" void kernel_launch(void* const* d_in, const int* in_sizes, int n_in,
                              void* d_out, int out_size, void* d_ws, size_t ws_size,
                              hipStream_t stream)
{
    (void)in_sizes; (void)n_in; (void)out_size; (void)ws_size;
    const float* hid   = (const float*)d_in[0];
    const float* Wq    = (const float*)d_in[1];
    const float* Wk    = (const float*)d_in[2];
    const float* Wv    = (const float*)d_in[3];
    const float* Wb    = (const float*)d_in[4];
    const float* cq    = (const float*)d_in[5];
    const float* ck    = (const float*)d_in[6];
    const float* cv    = (const float*)d_in[7];
    const float* w3    = (const float*)d_in[8];
    const float* w15   = (const float*)d_in[9];
    const float* w31   = (const float*)d_in[10];
    const float* kmix  = (const float*)d_in[11];
    const float* cmix  = (const float*)d_in[12];
    const float* fw1   = (const float*)d_in[13];
    const float* fb1   = (const float*)d_in[14];
    const float* fw2   = (const float*)d_in[15];
    const float* fb2   = (const float*)d_in[16];
    const float* onw   = (const float*)d_in[17];
    const float* Wo    = (const float*)d_in[18];
    float* out = (float*)d_out;

    // ---- workspace carve (peak ~195 MiB) ----
    const size_t MiB = 1024 * 1024;
    char* W = (char*)d_ws;
    float*  s0    = (float*)(W);              // qlin -> u(f32) -> yms[lo] -> hdn16
    char*   s1c   = W + 32 * MiB;             // qtmp -> w16|kT16 -> yms[hi] -> msout
    float*  s1    = (float*)s1c;
    float*  s2    = (float*)(W + 64 * MiB);   // vlin -> dt
    char*   s3    = W + 96 * MiB;             // q16|k16 -> mix16|ofin16
    float*  s4    = (float*)(W + 128 * MiB);  // v (long-lived)
    ushort* hid16 = (ushort*)(W + 160 * MiB);
    ushort* WqT   = (ushort*)(W + 176 * MiB);
    ushort* WkT   = WqT   + 1024 * 1024;
    ushort* WvT   = WkT   + 1024 * 1024;
    ushort* cmixT = WvT   + 1024 * 1024;
    ushort* WoT   = cmixT + 1024 * 1024;
    ushort* fw1T  = WoT   + 1024 * 1024;      // [2048][1024]
    ushort* kmixT = fw1T  + 2048 * 1024;      // [256][768]
    float*  beta  = (float*)(W + 191 * MiB);  // 128 KB
    ushort* al16  = (ushort*)(W + 191 * MiB + 128 * 1024);  // 2 MiB
    float*  bnf   = (float*)(W + 193 * MiB + 128 * 1024);   // 384 KB
    float*  wts   = bnf + 98304;                            // 384 KB

    ushort* q16    = (ushort*)s3;
    ushort* k16    = (ushort*)(s3 + 16 * MiB);
    ushort* mix16  = q16;
    ushort* ofin16 = k16;
    ushort* yms16  = (ushort*)s0;             // 48 MiB spans s0+s1
    ushort* hdn16  = (ushort*)s0;
    float*  qlin = s0; float* qtmp = s1;
    float*  u = s0;
    ushort* w16  = (ushort*)s1c;              // 16 MiB
    ushort* kT16 = (ushort*)(s1c + 16 * MiB); // 16 MiB
    float*  dt = s2; float* v = s4; float* msout = s1;

    const dim3 T256(256);
    // 0. casts / weight transposes
    cast_bf16<<<8192, T256, 0, stream>>>(hid, hid16);
    transpose_cast<<<dim3(32, 32), T256, 0, stream>>>(Wq, WqT, 1024, 1024);
    transpose_cast<<<dim3(32, 32), T256, 0, stream>>>(Wk, WkT, 1024, 1024);
    transpose_cast<<<dim3(32, 32), T256, 0, stream>>>(Wv, WvT, 1024, 1024);
    transpose_cast<<<dim3(32, 32), T256, 0, stream>>>(cmix, cmixT, 1024, 1024);
    transpose_cast<<<dim3(32, 32), T256, 0, stream>>>(Wo, WoT, 1024, 1024);
    transpose_cast<<<dim3(64, 32), T256, 0, stream>>>(fw1, fw1T, 1024, 2048);
    transpose_cast<<<dim3(8, 24), T256, 0, stream>>>(kmix, kmixT, 768, 256);
    // 1. q pipeline
    gemm_mfma<0><<<dim3(8, 64), T256, 0, stream>>>(hid16, WqT, nullptr, nullptr, nullptr, qlin, 8192, 1024, 1024);
    conv4_silu<<<32768, T256, 0, stream>>>(qlin, cq, qtmp);
    l2norm_bf16<<<8192, T256, 0, stream>>>(qtmp, q16);
    // 2. k pipeline
    gemm_mfma<0><<<dim3(8, 64), T256, 0, stream>>>(hid16, WkT, nullptr, nullptr, nullptr, qlin, 8192, 1024, 1024);
    conv4_silu<<<32768, T256, 0, stream>>>(qlin, ck, qtmp);
    l2norm_bf16<<<8192, T256, 0, stream>>>(qtmp, k16);
    // 3. v pipeline
    gemm_mfma<0><<<dim3(8, 64), T256, 0, stream>>>(hid16, WvT, nullptr, nullptr, nullptr, qlin, 8192, 1024, 1024);
    conv4_silu<<<32768, T256, 0, stream>>>(qlin, cv, v);
    // 4. beta
    gemm_smallN<4, 0><<<8192, T256, 0, stream>>>(hid, Wb, nullptr, beta, 1024);
    // 5. delta rule: prep + MFMA scan
    chunk_prep<<<1024, T256, 0, stream>>>(q16, k16, v, beta, u, w16, kT16, al16);
    delta_scan_mfma<<<256, dim3(64), 0, stream>>>(q16, kT16, w16, u, al16, dt);
    // 6. multiscale conv branch
    ms_conv<<<98304, T256, 0, stream>>>(v, w3, w15, w31, yms16);
    gemm_mfma<1><<<dim3(2, 256), T256, 0, stream>>>(yms16, kmixT, nullptr, nullptr, nullptr, mix16, 32768, 256, 768);
    gemm_mfma<0><<<dim3(8, 64), T256, 0, stream>>>(mix16, cmixT, nullptr, nullptr, nullptr, msout, 8192, 1024, 1024);
    // 7. fusion gate
    build_bn<<<8192, T256, 0, stream>>>(msout, dt, v, bnf);
    gemm_mfma<3><<<dim3(16, 64), T256, 0, stream>>>(hid16, fw1T, fb1, bnf, fw1 + 1024L * 2048, hdn16, 8192, 2048, 1024);
    gemm_smallN<12, 1><<<8192, T256, 0, stream>>>(hdn16, fw2, fb2, wts, 2048);
    // 8. blend + output projection
    blend_rms<<<8192, T256, 0, stream>>>(msout, dt, v, wts, onw, ofin16);
    gemm_mfma<0><<<dim3(8, 64), T256, 0, stream>>>(ofin16, WoT, nullptr, nullptr, nullptr, out, 8192, 1024, 1024);
}

// Round 5
// 1996.653 us; speedup vs baseline: 2.1197x; 1.0007x over previous
//
#include <hip/hip_runtime.h>
#include <math.h>

// Problem constants: B=4, L=2048, D=1024, H=4, dk=dv=256, CHUNK=32, NCHUNK=64
// bf16 MFMA for all large GEMMs AND the delta-rule scan.

typedef __attribute__((ext_vector_type(8))) __bf16 bf16x8;
typedef __attribute__((ext_vector_type(4))) float f32x4;

__device__ inline ushort f2bf(float f) {
    union { float f; unsigned u; } x; x.f = f;
    unsigned u = x.u;
    u += 0x7fffu + ((u >> 16) & 1u);
    return (ushort)(u >> 16);
}
__device__ inline float bf2f(ushort h) {
    union { unsigned u; float f; } x; x.u = ((unsigned)h) << 16;
    return x.f;
}
__device__ inline float ldf(float v) { return v; }
__device__ inline float ldf(ushort v) { return bf2f(v); }

// ---------------------------------------------------------------------------
// bf16 MFMA GEMM: C[M,N] = A[M,K] @ BT[N,K]^T. 128x128 tile, BK=32, 4 waves.
// EPI 0: f32 out. 1: bf16 out. 3: bias+rank12+gelu, bf16 out.
// ---------------------------------------------------------------------------
template<int EPI>
__global__ __launch_bounds__(256) void gemm_mfma(
    const ushort* __restrict__ A, const ushort* __restrict__ BT,
    const float* __restrict__ bias, const float* __restrict__ extA,
    const float* __restrict__ extB, void* __restrict__ Cout,
    int M, int N, int K)
{
    __shared__ ushort As[128 * 32];
    __shared__ ushort Bs[128 * 32];
    __shared__ float bns[(EPI >= 2) ? 128 * 13 : 1];
    __shared__ float exb[(EPI >= 2) ? 12 * 128 : 1];
    const int tid = threadIdx.x;
    const int row0 = blockIdx.y * 128, col0 = blockIdx.x * 128;
    const int lane = tid & 63, wave = tid >> 6;
    const int wr = (wave >> 1) * 64, wc = (wave & 1) * 64;

    if (EPI >= 2) {
        for (int e = tid; e < 128 * 12; e += 256)
            bns[(e / 12) * 13 + (e % 12)] = extA[(long)(row0 + e / 12) * 12 + e % 12];
        for (int e = tid; e < 12 * 128; e += 256)
            exb[e] = extB[(long)(e >> 7) * N + col0 + (e & 127)];
    }

    f32x4 acc[4][4];
    #pragma unroll
    for (int m = 0; m < 4; ++m)
        #pragma unroll
        for (int n = 0; n < 4; ++n) {
            acc[m][n][0] = 0.f; acc[m][n][1] = 0.f;
            acc[m][n][2] = 0.f; acc[m][n][3] = 0.f;
        }

    const int rA = lane & 15;
    const int ko = (lane >> 4) * 8;
    const int srow = tid >> 2;
    const int skk = (tid & 3) * 8;

    for (int k0 = 0; k0 < K; k0 += 32) {
        #pragma unroll
        for (int i = 0; i < 2; ++i) {
            const long ga = (long)(row0 + i * 64 + srow) * K + k0 + skk;
            __builtin_amdgcn_global_load_lds(
                (const __attribute__((address_space(1))) void*)(A + ga),
                (__attribute__((address_space(3))) void*)(As + i * 2048 + wave * 512),
                16, 0, 0);
            const long gb = (long)(col0 + i * 64 + srow) * K + k0 + skk;
            __builtin_amdgcn_global_load_lds(
                (const __attribute__((address_space(1))) void*)(BT + gb),
                (__attribute__((address_space(3))) void*)(Bs + i * 2048 + wave * 512),
                16, 0, 0);
        }
        __syncthreads();
        bf16x8 af[4], bfr[4];
        #pragma unroll
        for (int m = 0; m < 4; ++m)
            af[m] = *(const bf16x8*)(As + (wr + m * 16 + rA) * 32 + ko);
        #pragma unroll
        for (int n = 0; n < 4; ++n)
            bfr[n] = *(const bf16x8*)(Bs + (wc + n * 16 + rA) * 32 + ko);
        #pragma unroll
        for (int m = 0; m < 4; ++m)
            #pragma unroll
            for (int n = 0; n < 4; ++n)
                acc[m][n] = __builtin_amdgcn_mfma_f32_16x16x32_bf16(af[m], bfr[n], acc[m][n], 0, 0, 0);
        __syncthreads();
    }

    const int crow = (lane >> 4) * 4;
    const int ccol = lane & 15;
    #pragma unroll
    for (int m = 0; m < 4; ++m) {
        #pragma unroll
        for (int n = 0; n < 4; ++n) {
            #pragma unroll
            for (int r = 0; r < 4; ++r) {
                const int rl = wr + m * 16 + crow + r;
                const int cl = wc + n * 16 + ccol;
                float vv = acc[m][n][r];
                if (EPI >= 2) {
                    vv += bias[col0 + cl];
                    #pragma unroll
                    for (int j = 0; j < 12; ++j) vv += bns[rl * 13 + j] * exb[j * 128 + cl];
                    vv = 0.5f * vv * (1.f + erff(vv * 0.70710678118654752f));
                }
                const long off = (long)(row0 + rl) * N + col0 + cl;
                if (EPI == 0) ((float*)Cout)[off] = vv;
                else ((ushort*)Cout)[off] = f2bf(vv);
            }
        }
    }
}

// ---------------------------------------------------------------------------
// Transpose + cast to bf16: W[K][N] f32 -> WT[N][K] bf16.
// ---------------------------------------------------------------------------
__global__ __launch_bounds__(256) void transpose_cast(const float* __restrict__ W,
    ushort* __restrict__ WT, int K, int N)
{
    __shared__ float t[32][33];
    const int k0 = blockIdx.y * 32, n0 = blockIdx.x * 32;
    const int c = threadIdx.x & 31, r8 = threadIdx.x >> 5;
    #pragma unroll
    for (int rr = 0; rr < 4; ++rr) {
        const int r = r8 + rr * 8;
        t[r][c] = W[(long)(k0 + r) * N + n0 + c];
    }
    __syncthreads();
    #pragma unroll
    for (int rr = 0; rr < 4; ++rr) {
        const int r = r8 + rr * 8;
        WT[(long)(n0 + r) * K + k0 + c] = f2bf(t[c][r]);
    }
}

__global__ __launch_bounds__(256) void cast_bf16(const float* __restrict__ x,
    ushort* __restrict__ y)
{
    const long i = ((long)blockIdx.x * 256 + threadIdx.x) * 4;
    const float4 v = *(const float4*)(x + i);
    ushort4 o;
    o.x = f2bf(v.x); o.y = f2bf(v.y); o.z = f2bf(v.z); o.w = f2bf(v.w);
    *(ushort4*)(y + i) = o;
}

// ---------------------------------------------------------------------------
// Small-N GEMM. MODE 0: sigmoid. MODE 1: +bias, per-head softmax over triples.
// ---------------------------------------------------------------------------
template<int NOUT, int MODE, typename TA>
__global__ __launch_bounds__(256) void gemm_smallN(const TA* __restrict__ A,
    const float* __restrict__ Bm, const float* __restrict__ bias,
    float* __restrict__ Cm, int K)
{
    __shared__ float part[4][NOUT];
    __shared__ float sm[NOUT];
    const int m = blockIdx.x, tid = threadIdx.x;
    const TA* ar = A + (long)m * K;
    float acc[NOUT];
    #pragma unroll
    for (int j = 0; j < NOUT; ++j) acc[j] = 0.f;
    for (int k = tid; k < K; k += 256) {
        const float a = ldf(ar[k]);
        #pragma unroll
        for (int j = 0; j < NOUT; ++j) acc[j] += a * Bm[(long)k * NOUT + j];
    }
    #pragma unroll
    for (int j = 0; j < NOUT; ++j)
        for (int off = 32; off > 0; off >>= 1) acc[j] += __shfl_down(acc[j], off);
    const int wid = tid >> 6, lane = tid & 63;
    if (lane == 0) {
        #pragma unroll
        for (int j = 0; j < NOUT; ++j) part[wid][j] = acc[j];
    }
    __syncthreads();
    if (tid < NOUT) {
        float s = part[0][tid] + part[1][tid] + part[2][tid] + part[3][tid];
        if (MODE == 0) {
            Cm[(long)m * NOUT + tid] = 1.f / (1.f + expf(-s));
        } else {
            sm[tid] = s + bias[tid];
        }
    }
    if (MODE == 1) {
        __syncthreads();
        if (tid < NOUT) {
            const int hh = tid / 3, r = tid - hh * 3;
            const float a0 = sm[hh * 3], a1 = sm[hh * 3 + 1], a2 = sm[hh * 3 + 2];
            const float mx = fmaxf(a0, fmaxf(a1, a2));
            const float e0 = expf(a0 - mx), e1 = expf(a1 - mx), e2 = expf(a2 - mx);
            const float mine = (r == 0) ? e0 : ((r == 1) ? e1 : e2);
            Cm[(long)m * NOUT + tid] = mine / (e0 + e1 + e2);
        }
    }
}

// ---------------------------------------------------------------------------
// Depthwise causal conv (k=4) + SiLU, fp32 -> fp32.
// ---------------------------------------------------------------------------
__global__ __launch_bounds__(256) void conv4_silu(const float* __restrict__ x,
    const float* __restrict__ wc, float* __restrict__ y)
{
    const long idx = (long)blockIdx.x * 256 + threadIdx.x;
    const int c = (int)(idx & 1023);
    const long bl = idx >> 10;
    const int l = (int)(bl & 2047);
    const long b = bl >> 11;
    const float* xp = x + b * 2048 * 1024 + c;
    const float* wp = wc + c * 4;
    float s = 0.f;
    #pragma unroll
    for (int t = 0; t < 4; ++t) {
        const int ll = l - 3 + t;
        if (ll >= 0) s += xp[(long)ll * 1024] * wp[t];
    }
    y[idx] = s / (1.f + expf(-s));
}

// ---------------------------------------------------------------------------
// l2 normalize rows of 256 (fp32 in), write bf16.
// ---------------------------------------------------------------------------
__global__ __launch_bounds__(256) void l2norm_bf16(const float* __restrict__ x,
    ushort* __restrict__ y)
{
    const long wid = ((long)blockIdx.x * 256 + threadIdx.x) >> 6;
    const int lane = threadIdx.x & 63;
    const float4 xv = *(const float4*)(x + wid * 256 + lane * 4);
    float ss = xv.x * xv.x + xv.y * xv.y + xv.z * xv.z + xv.w * xv.w;
    for (int off = 32; off > 0; off >>= 1) ss += __shfl_down(ss, off);
    ss = __shfl(ss, 0);
    const float inv = rsqrtf(ss + 1e-6f);
    ushort4 o;
    o.x = f2bf(xv.x * inv); o.y = f2bf(xv.y * inv);
    o.z = f2bf(xv.z * inv); o.w = f2bf(xv.w * inv);
    *(ushort4*)(y + wid * 256 + lane * 4) = o;
}

// ---------------------------------------------------------------------------
// Chunk prep. Outputs: u (f32), w16 [blk][32][256] bf16, kT16 [blk][256][32]
// bf16, al16 [blk][32][32] bf16.
// ---------------------------------------------------------------------------
__global__ __launch_bounds__(256) void chunk_prep(
    const ushort* __restrict__ qn, const ushort* __restrict__ kn,
    const float* __restrict__ v, const float* __restrict__ beta,
    float* __restrict__ u, ushort* __restrict__ w16,
    ushort* __restrict__ kT16, ushort* __restrict__ al16)
{
    __shared__ float kb_s[32 * 256];
    __shared__ float bufB[32 * 256];
    __shared__ float Ms[32 * 33];
    __shared__ float Rs[32 * 33];
    __shared__ float bet[32];
    const int blk = blockIdx.x;
    const int n = blk & 63;
    const int bh = blk >> 6;
    const int h = bh & 3;
    const int b = bh >> 2;
    const int tid = threadIdx.x;
    const long lbase = (long)b * 2048 + n * 32;

    if (tid < 32) bet[tid] = beta[(lbase + tid) * 4 + h];
    __syncthreads();
    for (int e = tid; e < 8192; e += 256) {
        const int c = e >> 8, dd = e & 255;
        const float kv = bf2f(kn[(lbase + c) * 1024 + h * 256 + dd]);
        bufB[dd * 32 + c] = kv;
        kb_s[c * 256 + dd] = kv * bet[c];
    }
    __syncthreads();
    for (int e = tid; e < 8192; e += 256)
        kT16[(long)blk * 8192 + e] = f2bf(bufB[e]);

    const int j = tid & 31, i0 = tid >> 5;
    {
        float m4[4] = {0.f, 0.f, 0.f, 0.f};
        for (int dd = 0; dd < 256; ++dd) {
            const float kt = bufB[dd * 32 + j];
            #pragma unroll
            for (int ii = 0; ii < 4; ++ii) m4[ii] += kb_s[(i0 + 8 * ii) * 256 + dd] * kt;
        }
        #pragma unroll
        for (int ii = 0; ii < 4; ++ii) {
            const int i = i0 + 8 * ii;
            const float mv = (i > j) ? -m4[ii] : 0.f;
            Ms[i * 33 + j] = mv;
            Rs[i * 33 + j] = mv + ((i == j) ? 1.f : 0.f);
        }
    }
    {
        float a4[4] = {0.f, 0.f, 0.f, 0.f};
        for (int dd = 0; dd < 256; ++dd) {
            const float kt = bufB[dd * 32 + j];
            #pragma unroll
            for (int ii = 0; ii < 4; ++ii)
                a4[ii] += bf2f(qn[(lbase + (i0 + 8 * ii)) * 1024 + h * 256 + dd]) * kt;
        }
        #pragma unroll
        for (int ii = 0; ii < 4; ++ii) {
            const int i = i0 + 8 * ii;
            al16[(long)blk * 1024 + i * 32 + j] = f2bf((i >= j) ? a4[ii] : 0.f);
        }
    }
    __syncthreads();
    for (int it = 0; it < 4; ++it) {
        float p4[4] = {0.f, 0.f, 0.f, 0.f};
        for (int kk = 0; kk < 32; ++kk) {
            const float pb = Ms[kk * 33 + j];
            #pragma unroll
            for (int ii = 0; ii < 4; ++ii) p4[ii] += Ms[(i0 + 8 * ii) * 33 + kk] * pb;
        }
        __syncthreads();
        #pragma unroll
        for (int ii = 0; ii < 4; ++ii) Ms[(i0 + 8 * ii) * 33 + j] = p4[ii];
        __syncthreads();
        float r4[4] = {0.f, 0.f, 0.f, 0.f};
        for (int kk = 0; kk < 32; ++kk) {
            const float pb = Ms[kk * 33 + j];
            #pragma unroll
            for (int ii = 0; ii < 4; ++ii) r4[ii] += Rs[(i0 + 8 * ii) * 33 + kk] * pb;
        }
        __syncthreads();
        #pragma unroll
        for (int ii = 0; ii < 4; ++ii) Rs[(i0 + 8 * ii) * 33 + j] += r4[ii];
        __syncthreads();
    }
    for (int e = tid; e < 8192; e += 256) {
        const int c = e >> 8, dd = e & 255;
        bufB[c * 256 + dd] = v[(lbase + c) * 1024 + h * 256 + dd] * bet[c];
    }
    __syncthreads();
    {
        const int dd = tid;
        float accU[32], accW[32];
        #pragma unroll
        for (int r = 0; r < 32; ++r) { accU[r] = 0.f; accW[r] = 0.f; }
        for (int kk = 0; kk < 32; ++kk) {
            const float vv = bufB[kk * 256 + dd];
            const float bb = kb_s[kk * 256 + dd];
            #pragma unroll
            for (int r = 0; r < 32; ++r) {
                const float rr = Rs[r * 33 + kk];
                accU[r] += rr * vv;
                accW[r] += rr * bb;
            }
        }
        const long base = (long)blk * 32;
        #pragma unroll
        for (int r = 0; r < 32; ++r) {
            u  [(base + r) * 256 + dd] = accU[r];
            w16[(base + r) * 256 + dd] = f2bf(accW[r]);
        }
    }
}

// ---------------------------------------------------------------------------
// MFMA delta scan, 8-wave blocks for SIMD latency hiding.
// Grid = 32 blocks x 512 threads. Block -> (bh, dv-half) via XCD-folded map:
//   bh = (blk&7)*2 + (blk>>4), half = (blk>>3)&1  (both halves of a bh share
//   an XCD L2; heuristic only). Wave wv (0..7) owns dv-slice sl = half*8+wv.
// Per-wave code identical to round-3 scan (verified): S-slice (256x16) in
// MFMA accumulators; per chunk u' = u - w@S ; o = q@S + aloc@u' ; S += kT@u'.
// S and u' round-trip per-wave LDS in bf16 for B-operand fragment layout.
// ---------------------------------------------------------------------------
__global__ __launch_bounds__(512) void delta_scan_mfma(
    const ushort* __restrict__ q16, const ushort* __restrict__ kT16,
    const ushort* __restrict__ w16, const float* __restrict__ u,
    const ushort* __restrict__ al16, float* __restrict__ dt)
{
    __shared__ ushort Sb[8][16 * 264];   // per-wave: Sb[wv][col*264 + dd]
    __shared__ ushort Ub[8][16 * 40];    // per-wave: Ub[wv][col*40 + c]
    const int blk = blockIdx.x;
    const int bh = (blk & 7) * 2 + (blk >> 4);
    const int half = (blk >> 3) & 1;
    const int tid = threadIdx.x;
    const int wv = tid >> 6;
    const int lane = tid & 63;
    const int sl = half * 8 + wv;
    const int h = bh & 3;
    const int b = bh >> 2;
    const int v0 = sl * 16;
    const int col = lane & 15;
    const int grp = lane >> 4;

    f32x4 S[16];
    #pragma unroll
    for (int t = 0; t < 16; ++t) { S[t][0] = 0.f; S[t][1] = 0.f; S[t][2] = 0.f; S[t][3] = 0.f; }
    for (int i = lane; i < 16 * 264; i += 64) Sb[wv][i] = 0;
    __syncthreads();

    const ushort* wp  = w16  + ((long)bh * 64 * 32 + col) * 256 + grp * 8;
    const ushort* qp  = q16  + ((long)b * 2048 + col) * 1024 + h * 256 + grp * 8;
    const ushort* kp  = kT16 + ((long)bh * 64 * 256 + col) * 32 + grp * 8;
    const ushort* ap  = al16 + ((long)bh * 64 * 32 + col) * 32 + grp * 8;
    const float*  upt = u    + ((long)bh * 64 * 32 + grp * 4) * 256 + v0 + col;
    float*        dp  = dt   + ((long)b * 2048 + grp * 4) * 1024 + h * 256 + v0 + col;

    for (int n = 0; n < 64; ++n) {
        // --- read S B-frags (col-major S in Sb)
        bf16x8 sf[8];
        #pragma unroll
        for (int kb = 0; kb < 8; ++kb)
            sf[kb] = *(const bf16x8*)&Sb[wv][col * 264 + kb * 32 + grp * 8];

        // --- u' = u - w@S
        f32x4 up[2];
        #pragma unroll
        for (int rt = 0; rt < 2; ++rt) {
            f32x4 a; a[0] = 0.f; a[1] = 0.f; a[2] = 0.f; a[3] = 0.f;
            #pragma unroll
            for (int kb = 0; kb < 8; ++kb) {
                const bf16x8 wf = *(const bf16x8*)(wp + (long)n * 8192 + rt * 4096 + kb * 32);
                a = __builtin_amdgcn_mfma_f32_16x16x32_bf16(wf, sf[kb], a, 0, 0, 0);
            }
            #pragma unroll
            for (int r = 0; r < 4; ++r)
                up[rt][r] = upt[(long)n * 8192 + rt * 4096 + r * 256] - a[r];
        }
        // --- write u' (bf16, col-major) to Ub
        #pragma unroll
        for (int rt = 0; rt < 2; ++rt) {
            ushort4 p;
            p.x = f2bf(up[rt][0]); p.y = f2bf(up[rt][1]);
            p.z = f2bf(up[rt][2]); p.w = f2bf(up[rt][3]);
            *(ushort4*)&Ub[wv][col * 40 + rt * 16 + grp * 4] = p;
        }
        __syncthreads();
        const bf16x8 uf = *(const bf16x8*)&Ub[wv][col * 40 + grp * 8];

        // --- o = q@S + aloc@u' ; store to dt
        #pragma unroll
        for (int rt = 0; rt < 2; ++rt) {
            f32x4 a; a[0] = 0.f; a[1] = 0.f; a[2] = 0.f; a[3] = 0.f;
            #pragma unroll
            for (int kb = 0; kb < 8; ++kb) {
                const bf16x8 qf = *(const bf16x8*)(qp + (long)n * 32768 + rt * 16384 + kb * 32);
                a = __builtin_amdgcn_mfma_f32_16x16x32_bf16(qf, sf[kb], a, 0, 0, 0);
            }
            const bf16x8 alf = *(const bf16x8*)(ap + (long)n * 1024 + rt * 512);
            a = __builtin_amdgcn_mfma_f32_16x16x32_bf16(alf, uf, a, 0, 0, 0);
            #pragma unroll
            for (int r = 0; r < 4; ++r)
                dp[(long)n * 32768 + rt * 16384 + r * 1024] = a[r];
        }

        // --- S += kT @ u'
        #pragma unroll
        for (int t = 0; t < 16; ++t) {
            const bf16x8 kf = *(const bf16x8*)(kp + (long)n * 8192 + t * 512);
            S[t] = __builtin_amdgcn_mfma_f32_16x16x32_bf16(kf, uf, S[t], 0, 0, 0);
        }

        // --- write S (bf16, col-major) to Sb for next chunk
        __syncthreads();
        #pragma unroll
        for (int t = 0; t < 16; ++t) {
            ushort4 p;
            p.x = f2bf(S[t][0]); p.y = f2bf(S[t][1]);
            p.z = f2bf(S[t][2]); p.w = f2bf(S[t][3]);
            *(ushort4*)&Sb[wv][col * 264 + t * 16 + grp * 4] = p;
        }
        __syncthreads();
    }
}

// ---------------------------------------------------------------------------
// Multiscale causal depthwise conv -> bf16 out, torch-faithful layout.
// ---------------------------------------------------------------------------
__global__ __launch_bounds__(256) void ms_conv(const float* __restrict__ v,
    const float* __restrict__ w3, const float* __restrict__ w15,
    const float* __restrict__ w31, ushort* __restrict__ y)
{
    const long idx = (long)blockIdx.x * 256 + threadIdx.x;
    const int jj = (int)(idx % 768);
    const long t = idx / 768;
    const int h = (int)(t & 3);
    const long bl = t >> 2;
    const int l = (int)(bl & 2047);
    const long b = bl >> 11;
    const int cat = h * 768 + jj;
    const int sc = cat >> 10;
    const int c = cat & 1023;
    const float* xp = v + b * 2048 * 1024 + c;
    float s = 0.f;
    if (sc == 0) {
        const float* wp = w3 + c * 3;
        #pragma unroll
        for (int t2 = 0; t2 < 3; ++t2) {
            const int ll = l - 2 + t2;
            if (ll >= 0) s += xp[(long)ll * 1024] * wp[t2];
        }
    } else if (sc == 1) {
        const float* wp = w15 + c * 15;
        #pragma unroll
        for (int t2 = 0; t2 < 15; ++t2) {
            const int ll = l - 14 + t2;
            if (ll >= 0) s += xp[(long)ll * 1024] * wp[t2];
        }
    } else {
        const float* wp = w31 + c * 31;
        #pragma unroll
        for (int t2 = 0; t2 < 31; ++t2) {
            const int ll = l - 30 + t2;
            if (ll >= 0) s += xp[(long)ll * 1024] * wp[t2];
        }
    }
    y[idx] = f2bf(s);
}

// ---------------------------------------------------------------------------
// bn features: bn[bl,12] = [mean|ms| | mean|dt| | mean|v|] per head.
// ---------------------------------------------------------------------------
__global__ __launch_bounds__(256) void build_bn(const float* __restrict__ ms,
    const float* __restrict__ dt, const float* __restrict__ v,
    float* __restrict__ bn)
{
    const int bl = blockIdx.x, tid = threadIdx.x;
    const long rb = (long)bl * 1024;
    const int wid = tid >> 6, lane = tid & 63;
    const long base = rb + wid * 256 + lane * 4;
    float* g = bn + (long)bl * 12;
    float4 a;
    float s;
    a = *(const float4*)(ms + base);
    s = fabsf(a.x) + fabsf(a.y) + fabsf(a.z) + fabsf(a.w);
    for (int off = 32; off > 0; off >>= 1) s += __shfl_down(s, off);
    if (lane == 0) g[wid] = s * (1.f / 256.f);
    a = *(const float4*)(dt + base);
    s = fabsf(a.x) + fabsf(a.y) + fabsf(a.z) + fabsf(a.w);
    for (int off = 32; off > 0; off >>= 1) s += __shfl_down(s, off);
    if (lane == 0) g[4 + wid] = s * (1.f / 256.f);
    a = *(const float4*)(v + base);
    s = fabsf(a.x) + fabsf(a.y) + fabsf(a.z) + fabsf(a.w);
    for (int off = 32; off > 0; off >>= 1) s += __shfl_down(s, off);
    if (lane == 0) g[8 + wid] = s * (1.f / 256.f);
}

// ---------------------------------------------------------------------------
// Blend + per-head RMSNorm * o_norm_w -> bf16 out.
// ---------------------------------------------------------------------------
__global__ __launch_bounds__(256) void blend_rms(const float* __restrict__ ms,
    const float* __restrict__ dt, const float* __restrict__ v,
    const float* __restrict__ wts, const float* __restrict__ onw,
    ushort* __restrict__ o)
{
    const int bl = blockIdx.x, tid = threadIdx.x;
    const int wid = tid >> 6, lane = tid & 63;
    const long base = (long)bl * 1024 + wid * 256 + lane * 4;
    const float* wr = wts + (long)bl * 12 + wid * 3;
    const float w0 = wr[0], w1 = wr[1], w2 = wr[2];
    const float4 m = *(const float4*)(ms + base);
    const float4 d = *(const float4*)(dt + base);
    const float4 x = *(const float4*)(v + base);
    float4 ov;
    ov.x = w0 * m.x + w1 * d.x + w2 * x.x;
    ov.y = w0 * m.y + w1 * d.y + w2 * x.y;
    ov.z = w0 * m.z + w1 * d.z + w2 * x.z;
    ov.w = w0 * m.w + w1 * d.w + w2 * x.w;
    float ss = ov.x * ov.x + ov.y * ov.y + ov.z * ov.z + ov.w * ov.w;
    for (int off = 32; off > 0; off >>= 1) ss += __shfl_down(ss, off);
    ss = __shfl(ss, 0);
    const float inv = rsqrtf(ss * (1.f / 256.f) + 1e-5f);
    const float4 nw = *(const float4*)(onw + lane * 4);
    ushort4 ob;
    ob.x = f2bf(ov.x * inv * nw.x); ob.y = f2bf(ov.y * inv * nw.y);
    ob.z = f2bf(ov.z * inv * nw.z); ob.w = f2bf(ov.w * inv * nw.w);
    *(ushort4*)(o + base) = ob;
}

// ---------------------------------------------------------------------------
extern "C" void kernel_launch(void* const* d_in, const int* in_sizes, int n_in,
                              void* d_out, int out_size, void* d_ws, size_t ws_size,
                              hipStream_t stream)
{
    (void)in_sizes; (void)n_in; (void)out_size; (void)ws_size;
    const float* hid   = (const float*)d_in[0];
    const float* Wq    = (const float*)d_in[1];
    const float* Wk    = (const float*)d_in[2];
    const float* Wv    = (const float*)d_in[3];
    const float* Wb    = (const float*)d_in[4];
    const float* cq    = (const float*)d_in[5];
    const float* ck    = (const float*)d_in[6];
    const float* cv    = (const float*)d_in[7];
    const float* w3    = (const float*)d_in[8];
    const float* w15   = (const float*)d_in[9];
    const float* w31   = (const float*)d_in[10];
    const float* kmix  = (const float*)d_in[11];
    const float* cmix  = (const float*)d_in[12];
    const float* fw1   = (const float*)d_in[13];
    const float* fb1   = (const float*)d_in[14];
    const float* fw2   = (const float*)d_in[15];
    const float* fb2   = (const float*)d_in[16];
    const float* onw   = (const float*)d_in[17];
    const float* Wo    = (const float*)d_in[18];
    float* out = (float*)d_out;

    // ---- workspace carve (peak ~195 MiB) ----
    const size_t MiB = 1024 * 1024;
    char* W = (char*)d_ws;
    float*  s0    = (float*)(W);              // qlin -> u(f32) -> yms[lo] -> hdn16
    char*   s1c   = W + 32 * MiB;             // qtmp -> w16|kT16 -> yms[hi] -> msout
    float*  s1    = (float*)s1c;
    float*  s2    = (float*)(W + 64 * MiB);   // vlin -> dt
    char*   s3    = W + 96 * MiB;             // q16|k16 -> mix16|ofin16
    float*  s4    = (float*)(W + 128 * MiB);  // v (long-lived)
    ushort* hid16 = (ushort*)(W + 160 * MiB);
    ushort* WqT   = (ushort*)(W + 176 * MiB);
    ushort* WkT   = WqT   + 1024 * 1024;
    ushort* WvT   = WkT   + 1024 * 1024;
    ushort* cmixT = WvT   + 1024 * 1024;
    ushort* WoT   = cmixT + 1024 * 1024;
    ushort* fw1T  = WoT   + 1024 * 1024;      // [2048][1024]
    ushort* kmixT = fw1T  + 2048 * 1024;      // [256][768]
    float*  beta  = (float*)(W + 191 * MiB);  // 128 KB
    ushort* al16  = (ushort*)(W + 191 * MiB + 128 * 1024);  // 2 MiB
    float*  bnf   = (float*)(W + 193 * MiB + 128 * 1024);   // 384 KB
    float*  wts   = bnf + 98304;                            // 384 KB

    ushort* q16    = (ushort*)s3;
    ushort* k16    = (ushort*)(s3 + 16 * MiB);
    ushort* mix16  = q16;
    ushort* ofin16 = k16;
    ushort* yms16  = (ushort*)s0;             // 48 MiB spans s0+s1
    ushort* hdn16  = (ushort*)s0;
    float*  qlin = s0; float* qtmp = s1;
    float*  u = s0;
    ushort* w16  = (ushort*)s1c;              // 16 MiB
    ushort* kT16 = (ushort*)(s1c + 16 * MiB); // 16 MiB
    float*  dt = s2; float* v = s4; float* msout = s1;

    const dim3 T256(256);
    // 0. casts / weight transposes
    cast_bf16<<<8192, T256, 0, stream>>>(hid, hid16);
    transpose_cast<<<dim3(32, 32), T256, 0, stream>>>(Wq, WqT, 1024, 1024);
    transpose_cast<<<dim3(32, 32), T256, 0, stream>>>(Wk, WkT, 1024, 1024);
    transpose_cast<<<dim3(32, 32), T256, 0, stream>>>(Wv, WvT, 1024, 1024);
    transpose_cast<<<dim3(32, 32), T256, 0, stream>>>(cmix, cmixT, 1024, 1024);
    transpose_cast<<<dim3(32, 32), T256, 0, stream>>>(Wo, WoT, 1024, 1024);
    transpose_cast<<<dim3(64, 32), T256, 0, stream>>>(fw1, fw1T, 1024, 2048);
    transpose_cast<<<dim3(8, 24), T256, 0, stream>>>(kmix, kmixT, 768, 256);
    // 1. q pipeline
    gemm_mfma<0><<<dim3(8, 64), T256, 0, stream>>>(hid16, WqT, nullptr, nullptr, nullptr, qlin, 8192, 1024, 1024);
    conv4_silu<<<32768, T256, 0, stream>>>(qlin, cq, qtmp);
    l2norm_bf16<<<8192, T256, 0, stream>>>(qtmp, q16);
    // 2. k pipeline
    gemm_mfma<0><<<dim3(8, 64), T256, 0, stream>>>(hid16, WkT, nullptr, nullptr, nullptr, qlin, 8192, 1024, 1024);
    conv4_silu<<<32768, T256, 0, stream>>>(qlin, ck, qtmp);
    l2norm_bf16<<<8192, T256, 0, stream>>>(qtmp, k16);
    // 3. v pipeline
    gemm_mfma<0><<<dim3(8, 64), T256, 0, stream>>>(hid16, WvT, nullptr, nullptr, nullptr, qlin, 8192, 1024, 1024);
    conv4_silu<<<32768, T256, 0, stream>>>(qlin, cv, v);
    // 4. beta
    gemm_smallN<4, 0><<<8192, T256, 0, stream>>>(hid, Wb, nullptr, beta, 1024);
    // 5. delta rule: prep + MFMA scan (8-wave blocks)
    chunk_prep<<<1024, T256, 0, stream>>>(q16, k16, v, beta, u, w16, kT16, al16);
    delta_scan_mfma<<<32, dim3(512), 0, stream>>>(q16, kT16, w16, u, al16, dt);
    // 6. multiscale conv branch
    ms_conv<<<98304, T256, 0, stream>>>(v, w3, w15, w31, yms16);
    gemm_mfma<1><<<dim3(2, 256), T256, 0, stream>>>(yms16, kmixT, nullptr, nullptr, nullptr, mix16, 32768, 256, 768);
    gemm_mfma<0><<<dim3(8, 64), T256, 0, stream>>>(mix16, cmixT, nullptr, nullptr, nullptr, msout, 8192, 1024, 1024);
    // 7. fusion gate
    build_bn<<<8192, T256, 0, stream>>>(msout, dt, v, bnf);
    gemm_mfma<3><<<dim3(16, 64), T256, 0, stream>>>(hid16, fw1T, fb1, bnf, fw1 + 1024L * 2048, hdn16, 8192, 2048, 1024);
    gemm_smallN<12, 1><<<8192, T256, 0, stream>>>(hdn16, fw2, fb2, wts, 2048);
    // 8. blend + output projection
    blend_rms<<<8192, T256, 0, stream>>>(msout, dt, v, wts, onw, ofin16);
    gemm_mfma<0><<<dim3(8, 64), T256, 0, stream>>>(ofin16, WoT, nullptr, nullptr, nullptr, out, 8192, 1024, 1024);
}

// Round 6
// 875.865 us; speedup vs baseline: 4.8322x; 2.2796x over previous
//
#include <hip/hip_runtime.h>
#include <math.h>

// Problem constants: B=4, L=2048, D=1024, H=4, dk=dv=256, CHUNK=32, NCHUNK=64
// bf16 MFMA for all large GEMMs AND the delta-rule scan (LDS-staged, dbuf).

typedef __attribute__((ext_vector_type(8))) __bf16 bf16x8;
typedef __attribute__((ext_vector_type(4))) float f32x4;

__device__ inline ushort f2bf(float f) {
    union { float f; unsigned u; } x; x.f = f;
    unsigned u = x.u;
    u += 0x7fffu + ((u >> 16) & 1u);
    return (ushort)(u >> 16);
}
__device__ inline float bf2f(ushort h) {
    union { unsigned u; float f; } x; x.u = ((unsigned)h) << 16;
    return x.f;
}
__device__ inline float ldf(float v) { return v; }
__device__ inline float ldf(ushort v) { return bf2f(v); }

// ---------------------------------------------------------------------------
// bf16 MFMA GEMM: C[M,N] = A[M,K] @ BT[N,K]^T. 128x128 tile, BK=32, 4 waves.
// EPI 0: f32 out. 1: bf16 out. 3: bias+rank12+gelu, bf16 out.
// ---------------------------------------------------------------------------
template<int EPI>
__global__ __launch_bounds__(256) void gemm_mfma(
    const ushort* __restrict__ A, const ushort* __restrict__ BT,
    const float* __restrict__ bias, const float* __restrict__ extA,
    const float* __restrict__ extB, void* __restrict__ Cout,
    int M, int N, int K)
{
    __shared__ ushort As[128 * 32];
    __shared__ ushort Bs[128 * 32];
    __shared__ float bns[(EPI >= 2) ? 128 * 13 : 1];
    __shared__ float exb[(EPI >= 2) ? 12 * 128 : 1];
    const int tid = threadIdx.x;
    const int row0 = blockIdx.y * 128, col0 = blockIdx.x * 128;
    const int lane = tid & 63, wave = tid >> 6;
    const int wr = (wave >> 1) * 64, wc = (wave & 1) * 64;

    if (EPI >= 2) {
        for (int e = tid; e < 128 * 12; e += 256)
            bns[(e / 12) * 13 + (e % 12)] = extA[(long)(row0 + e / 12) * 12 + e % 12];
        for (int e = tid; e < 12 * 128; e += 256)
            exb[e] = extB[(long)(e >> 7) * N + col0 + (e & 127)];
    }

    f32x4 acc[4][4];
    #pragma unroll
    for (int m = 0; m < 4; ++m)
        #pragma unroll
        for (int n = 0; n < 4; ++n) {
            acc[m][n][0] = 0.f; acc[m][n][1] = 0.f;
            acc[m][n][2] = 0.f; acc[m][n][3] = 0.f;
        }

    const int rA = lane & 15;
    const int ko = (lane >> 4) * 8;
    const int srow = tid >> 2;
    const int skk = (tid & 3) * 8;

    for (int k0 = 0; k0 < K; k0 += 32) {
        #pragma unroll
        for (int i = 0; i < 2; ++i) {
            const long ga = (long)(row0 + i * 64 + srow) * K + k0 + skk;
            __builtin_amdgcn_global_load_lds(
                (const __attribute__((address_space(1))) void*)(A + ga),
                (__attribute__((address_space(3))) void*)(As + i * 2048 + wave * 512),
                16, 0, 0);
            const long gb = (long)(col0 + i * 64 + srow) * K + k0 + skk;
            __builtin_amdgcn_global_load_lds(
                (const __attribute__((address_space(1))) void*)(BT + gb),
                (__attribute__((address_space(3))) void*)(Bs + i * 2048 + wave * 512),
                16, 0, 0);
        }
        __syncthreads();
        bf16x8 af[4], bfr[4];
        #pragma unroll
        for (int m = 0; m < 4; ++m)
            af[m] = *(const bf16x8*)(As + (wr + m * 16 + rA) * 32 + ko);
        #pragma unroll
        for (int n = 0; n < 4; ++n)
            bfr[n] = *(const bf16x8*)(Bs + (wc + n * 16 + rA) * 32 + ko);
        #pragma unroll
        for (int m = 0; m < 4; ++m)
            #pragma unroll
            for (int n = 0; n < 4; ++n)
                acc[m][n] = __builtin_amdgcn_mfma_f32_16x16x32_bf16(af[m], bfr[n], acc[m][n], 0, 0, 0);
        __syncthreads();
    }

    const int crow = (lane >> 4) * 4;
    const int ccol = lane & 15;
    #pragma unroll
    for (int m = 0; m < 4; ++m) {
        #pragma unroll
        for (int n = 0; n < 4; ++n) {
            #pragma unroll
            for (int r = 0; r < 4; ++r) {
                const int rl = wr + m * 16 + crow + r;
                const int cl = wc + n * 16 + ccol;
                float vv = acc[m][n][r];
                if (EPI >= 2) {
                    vv += bias[col0 + cl];
                    #pragma unroll
                    for (int j = 0; j < 12; ++j) vv += bns[rl * 13 + j] * exb[j * 128 + cl];
                    vv = 0.5f * vv * (1.f + erff(vv * 0.70710678118654752f));
                }
                const long off = (long)(row0 + rl) * N + col0 + cl;
                if (EPI == 0) ((float*)Cout)[off] = vv;
                else ((ushort*)Cout)[off] = f2bf(vv);
            }
        }
    }
}

// ---------------------------------------------------------------------------
// Transpose + cast to bf16: W[K][N] f32 -> WT[N][K] bf16.
// ---------------------------------------------------------------------------
__global__ __launch_bounds__(256) void transpose_cast(const float* __restrict__ W,
    ushort* __restrict__ WT, int K, int N)
{
    __shared__ float t[32][33];
    const int k0 = blockIdx.y * 32, n0 = blockIdx.x * 32;
    const int c = threadIdx.x & 31, r8 = threadIdx.x >> 5;
    #pragma unroll
    for (int rr = 0; rr < 4; ++rr) {
        const int r = r8 + rr * 8;
        t[r][c] = W[(long)(k0 + r) * N + n0 + c];
    }
    __syncthreads();
    #pragma unroll
    for (int rr = 0; rr < 4; ++rr) {
        const int r = r8 + rr * 8;
        WT[(long)(n0 + r) * K + k0 + c] = f2bf(t[c][r]);
    }
}

__global__ __launch_bounds__(256) void cast_bf16(const float* __restrict__ x,
    ushort* __restrict__ y)
{
    const long i = ((long)blockIdx.x * 256 + threadIdx.x) * 4;
    const float4 v = *(const float4*)(x + i);
    ushort4 o;
    o.x = f2bf(v.x); o.y = f2bf(v.y); o.z = f2bf(v.z); o.w = f2bf(v.w);
    *(ushort4*)(y + i) = o;
}

// ---------------------------------------------------------------------------
// Small-N GEMM. MODE 0: sigmoid. MODE 1: +bias, per-head softmax over triples.
// ---------------------------------------------------------------------------
template<int NOUT, int MODE, typename TA>
__global__ __launch_bounds__(256) void gemm_smallN(const TA* __restrict__ A,
    const float* __restrict__ Bm, const float* __restrict__ bias,
    float* __restrict__ Cm, int K)
{
    __shared__ float part[4][NOUT];
    __shared__ float sm[NOUT];
    const int m = blockIdx.x, tid = threadIdx.x;
    const TA* ar = A + (long)m * K;
    float acc[NOUT];
    #pragma unroll
    for (int j = 0; j < NOUT; ++j) acc[j] = 0.f;
    for (int k = tid; k < K; k += 256) {
        const float a = ldf(ar[k]);
        #pragma unroll
        for (int j = 0; j < NOUT; ++j) acc[j] += a * Bm[(long)k * NOUT + j];
    }
    #pragma unroll
    for (int j = 0; j < NOUT; ++j)
        for (int off = 32; off > 0; off >>= 1) acc[j] += __shfl_down(acc[j], off);
    const int wid = tid >> 6, lane = tid & 63;
    if (lane == 0) {
        #pragma unroll
        for (int j = 0; j < NOUT; ++j) part[wid][j] = acc[j];
    }
    __syncthreads();
    if (tid < NOUT) {
        float s = part[0][tid] + part[1][tid] + part[2][tid] + part[3][tid];
        if (MODE == 0) {
            Cm[(long)m * NOUT + tid] = 1.f / (1.f + expf(-s));
        } else {
            sm[tid] = s + bias[tid];
        }
    }
    if (MODE == 1) {
        __syncthreads();
        if (tid < NOUT) {
            const int hh = tid / 3, r = tid - hh * 3;
            const float a0 = sm[hh * 3], a1 = sm[hh * 3 + 1], a2 = sm[hh * 3 + 2];
            const float mx = fmaxf(a0, fmaxf(a1, a2));
            const float e0 = expf(a0 - mx), e1 = expf(a1 - mx), e2 = expf(a2 - mx);
            const float mine = (r == 0) ? e0 : ((r == 1) ? e1 : e2);
            Cm[(long)m * NOUT + tid] = mine / (e0 + e1 + e2);
        }
    }
}

// ---------------------------------------------------------------------------
// Depthwise causal conv (k=4) + SiLU, fp32 -> fp32.
// ---------------------------------------------------------------------------
__global__ __launch_bounds__(256) void conv4_silu(const float* __restrict__ x,
    const float* __restrict__ wc, float* __restrict__ y)
{
    const long idx = (long)blockIdx.x * 256 + threadIdx.x;
    const int c = (int)(idx & 1023);
    const long bl = idx >> 10;
    const int l = (int)(bl & 2047);
    const long b = bl >> 11;
    const float* xp = x + b * 2048 * 1024 + c;
    const float* wp = wc + c * 4;
    float s = 0.f;
    #pragma unroll
    for (int t = 0; t < 4; ++t) {
        const int ll = l - 3 + t;
        if (ll >= 0) s += xp[(long)ll * 1024] * wp[t];
    }
    y[idx] = s / (1.f + expf(-s));
}

// ---------------------------------------------------------------------------
// l2 normalize rows of 256 (fp32 in), write bf16.
// ---------------------------------------------------------------------------
__global__ __launch_bounds__(256) void l2norm_bf16(const float* __restrict__ x,
    ushort* __restrict__ y)
{
    const long wid = ((long)blockIdx.x * 256 + threadIdx.x) >> 6;
    const int lane = threadIdx.x & 63;
    const float4 xv = *(const float4*)(x + wid * 256 + lane * 4);
    float ss = xv.x * xv.x + xv.y * xv.y + xv.z * xv.z + xv.w * xv.w;
    for (int off = 32; off > 0; off >>= 1) ss += __shfl_down(ss, off);
    ss = __shfl(ss, 0);
    const float inv = rsqrtf(ss + 1e-6f);
    ushort4 o;
    o.x = f2bf(xv.x * inv); o.y = f2bf(xv.y * inv);
    o.z = f2bf(xv.z * inv); o.w = f2bf(xv.w * inv);
    *(ushort4*)(y + wid * 256 + lane * 4) = o;
}

// ---------------------------------------------------------------------------
// Chunk prep. Outputs: u (f32), w16 [blk][32][256] bf16, kT16 [blk][256][32]
// bf16, al16 [blk][32][32] bf16.
// ---------------------------------------------------------------------------
__global__ __launch_bounds__(256) void chunk_prep(
    const ushort* __restrict__ qn, const ushort* __restrict__ kn,
    const float* __restrict__ v, const float* __restrict__ beta,
    float* __restrict__ u, ushort* __restrict__ w16,
    ushort* __restrict__ kT16, ushort* __restrict__ al16)
{
    __shared__ float kb_s[32 * 256];
    __shared__ float bufB[32 * 256];
    __shared__ float Ms[32 * 33];
    __shared__ float Rs[32 * 33];
    __shared__ float bet[32];
    const int blk = blockIdx.x;
    const int n = blk & 63;
    const int bh = blk >> 6;
    const int h = bh & 3;
    const int b = bh >> 2;
    const int tid = threadIdx.x;
    const long lbase = (long)b * 2048 + n * 32;

    if (tid < 32) bet[tid] = beta[(lbase + tid) * 4 + h];
    __syncthreads();
    for (int e = tid; e < 8192; e += 256) {
        const int c = e >> 8, dd = e & 255;
        const float kv = bf2f(kn[(lbase + c) * 1024 + h * 256 + dd]);
        bufB[dd * 32 + c] = kv;
        kb_s[c * 256 + dd] = kv * bet[c];
    }
    __syncthreads();
    for (int e = tid; e < 8192; e += 256)
        kT16[(long)blk * 8192 + e] = f2bf(bufB[e]);

    const int j = tid & 31, i0 = tid >> 5;
    {
        float m4[4] = {0.f, 0.f, 0.f, 0.f};
        for (int dd = 0; dd < 256; ++dd) {
            const float kt = bufB[dd * 32 + j];
            #pragma unroll
            for (int ii = 0; ii < 4; ++ii) m4[ii] += kb_s[(i0 + 8 * ii) * 256 + dd] * kt;
        }
        #pragma unroll
        for (int ii = 0; ii < 4; ++ii) {
            const int i = i0 + 8 * ii;
            const float mv = (i > j) ? -m4[ii] : 0.f;
            Ms[i * 33 + j] = mv;
            Rs[i * 33 + j] = mv + ((i == j) ? 1.f : 0.f);
        }
    }
    {
        float a4[4] = {0.f, 0.f, 0.f, 0.f};
        for (int dd = 0; dd < 256; ++dd) {
            const float kt = bufB[dd * 32 + j];
            #pragma unroll
            for (int ii = 0; ii < 4; ++ii)
                a4[ii] += bf2f(qn[(lbase + (i0 + 8 * ii)) * 1024 + h * 256 + dd]) * kt;
        }
        #pragma unroll
        for (int ii = 0; ii < 4; ++ii) {
            const int i = i0 + 8 * ii;
            al16[(long)blk * 1024 + i * 32 + j] = f2bf((i >= j) ? a4[ii] : 0.f);
        }
    }
    __syncthreads();
    for (int it = 0; it < 4; ++it) {
        float p4[4] = {0.f, 0.f, 0.f, 0.f};
        for (int kk = 0; kk < 32; ++kk) {
            const float pb = Ms[kk * 33 + j];
            #pragma unroll
            for (int ii = 0; ii < 4; ++ii) p4[ii] += Ms[(i0 + 8 * ii) * 33 + kk] * pb;
        }
        __syncthreads();
        #pragma unroll
        for (int ii = 0; ii < 4; ++ii) Ms[(i0 + 8 * ii) * 33 + j] = p4[ii];
        __syncthreads();
        float r4[4] = {0.f, 0.f, 0.f, 0.f};
        for (int kk = 0; kk < 32; ++kk) {
            const float pb = Ms[kk * 33 + j];
            #pragma unroll
            for (int ii = 0; ii < 4; ++ii) r4[ii] += Rs[(i0 + 8 * ii) * 33 + kk] * pb;
        }
        __syncthreads();
        #pragma unroll
        for (int ii = 0; ii < 4; ++ii) Rs[(i0 + 8 * ii) * 33 + j] += r4[ii];
        __syncthreads();
    }
    for (int e = tid; e < 8192; e += 256) {
        const int c = e >> 8, dd = e & 255;
        bufB[c * 256 + dd] = v[(lbase + c) * 1024 + h * 256 + dd] * bet[c];
    }
    __syncthreads();
    {
        const int dd = tid;
        float accU[32], accW[32];
        #pragma unroll
        for (int r = 0; r < 32; ++r) { accU[r] = 0.f; accW[r] = 0.f; }
        for (int kk = 0; kk < 32; ++kk) {
            const float vv = bufB[kk * 256 + dd];
            const float bb = kb_s[kk * 256 + dd];
            #pragma unroll
            for (int r = 0; r < 32; ++r) {
                const float rr = Rs[r * 33 + kk];
                accU[r] += rr * vv;
                accW[r] += rr * bb;
            }
        }
        const long base = (long)blk * 32;
        #pragma unroll
        for (int r = 0; r < 32; ++r) {
            u  [(base + r) * 256 + dd] = accU[r];
            w16[(base + r) * 256 + dd] = f2bf(accW[r]);
        }
    }
}

// ---------------------------------------------------------------------------
// MFMA delta scan, 256 x 1-wave blocks, LDS double-buffered operand staging.
// Block = (bh = blk&15, sl = blk>>4): all 16 slices of a bh share XCD blk&7.
// Per chunk (math identical to verified round-3/4 scan):
//   u' = u - w@S ; o = q@S + aloc@u' ; S += kT@u'
// w/q staged with XOR swizzle elem ^= ((row&7)<<3) (inverse-swizzled global
// source, swizzled LDS read) to avoid 16-way stride-512B bank conflicts.
// kT/al staged linearly. u prefetched to regs. Single wave: no barriers,
// one s_waitcnt vmcnt(0) per chunk (staging issued a full chunk ahead).
// LDS = 2*50KB staging + Sb 8.4KB + Ub 1.3KB = ~110KB.
// ---------------------------------------------------------------------------
__global__ __launch_bounds__(64) void delta_scan_mfma(
    const ushort* __restrict__ q16, const ushort* __restrict__ kT16,
    const ushort* __restrict__ w16, const float* __restrict__ u,
    const ushort* __restrict__ al16, float* __restrict__ dt)
{
    // staging layout (elem offsets): W 0 | Q 8192 | KT 16384 | AL 24576
    __shared__ __align__(16) ushort Stg[2][25600];
    __shared__ __align__(16) ushort Sb[16 * 264];
    __shared__ __align__(16) ushort Ub[16 * 40];
    const int blk = blockIdx.x;
    const int bh = blk & 15;
    const int sl = blk >> 4;
    const int h = bh & 3;
    const int b = bh >> 2;
    const int v0 = sl * 16;
    const int lane = threadIdx.x;
    const int col = lane & 15;
    const int grp = lane >> 4;
    const int l5 = lane & 31;
    const int lh = lane >> 5;

    f32x4 S[16];
    #pragma unroll
    for (int t = 0; t < 16; ++t) { S[t][0] = 0.f; S[t][1] = 0.f; S[t][2] = 0.f; S[t][3] = 0.f; }
    for (int i = lane; i < 16 * 264; i += 64) Sb[i] = 0;

    const ushort* Wg = w16  + (long)bh * 64 * 8192;
    const ushort* Qg = q16  + ((long)b * 2048) * 1024 + h * 256;
    const ushort* Kg = kT16 + (long)bh * 64 * 8192;
    const ushort* Ag = al16 + (long)bh * 64 * 1024;
    const float*  Ug = u    + (long)bh * 64 * 8192 + grp * 1024 + v0 + col;
    float*        dp = dt   + ((long)b * 2048 + grp * 4) * 1024 + h * 256 + v0 + col;

    // stage chunk n into buffer s
    auto STAGE = [&](int n, int s) {
        ushort* dst = &Stg[s][0];
        // W: 16 instrs, rows of 256 elems, swizzled source
        const ushort* wsrc = Wg + (long)n * 8192;
        #pragma unroll
        for (int i = 0; i < 16; ++i) {
            const int row = 2 * i + lh;
            const int key = row & 7;
            __builtin_amdgcn_global_load_lds(
                (const __attribute__((address_space(1))) void*)(wsrc + row * 256 + ((l5 ^ key) << 3)),
                (__attribute__((address_space(3))) void*)(dst + i * 512), 16, 0, 0);
        }
        // Q: 16 instrs, global row stride 1024 elems, swizzled source
        #pragma unroll
        for (int i = 0; i < 16; ++i) {
            const int row = 2 * i + lh;
            const int key = row & 7;
            __builtin_amdgcn_global_load_lds(
                (const __attribute__((address_space(1))) void*)(Qg + (long)(n * 32 + row) * 1024 + ((l5 ^ key) << 3)),
                (__attribute__((address_space(3))) void*)(dst + 8192 + i * 512), 16, 0, 0);
        }
        // KT: 16 instrs, linear
        const ushort* ksrc = Kg + (long)n * 8192;
        #pragma unroll
        for (int i = 0; i < 16; ++i)
            __builtin_amdgcn_global_load_lds(
                (const __attribute__((address_space(1))) void*)(ksrc + i * 512 + lane * 8),
                (__attribute__((address_space(3))) void*)(dst + 16384 + i * 512), 16, 0, 0);
        // AL: 2 instrs, linear
        const ushort* asrc = Ag + (long)n * 1024;
        #pragma unroll
        for (int i = 0; i < 2; ++i)
            __builtin_amdgcn_global_load_lds(
                (const __attribute__((address_space(1))) void*)(asrc + i * 512 + lane * 8),
                (__attribute__((address_space(3))) void*)(dst + 24576 + i * 512), 16, 0, 0);
    };

    const int xk = (col & 7) << 3;   // read-side swizzle key for W/Q

    STAGE(0, 0);
    for (int n = 0; n < 64; ++n) {
        const int s = n & 1;
        asm volatile("s_waitcnt vmcnt(0)" ::: "memory");
        __builtin_amdgcn_sched_barrier(0);
        // prefetch u for this chunk (8 f32) BEFORE issuing next staging
        float upre[8];
        #pragma unroll
        for (int rt = 0; rt < 2; ++rt)
            #pragma unroll
            for (int r = 0; r < 4; ++r)
                upre[rt * 4 + r] = Ug[(long)n * 8192 + rt * 4096 + r * 256];
        __builtin_amdgcn_sched_barrier(0);
        if (n < 63) STAGE(n + 1, s ^ 1);
        const ushort* Sg = &Stg[s][0];

        // --- read S B-frags (col-major S in Sb)
        bf16x8 sf[8];
        #pragma unroll
        for (int kb = 0; kb < 8; ++kb)
            sf[kb] = *(const bf16x8*)&Sb[col * 264 + kb * 32 + grp * 8];

        // --- u' = u - w@S
        f32x4 up[2];
        #pragma unroll
        for (int rt = 0; rt < 2; ++rt) {
            f32x4 a; a[0] = 0.f; a[1] = 0.f; a[2] = 0.f; a[3] = 0.f;
            #pragma unroll
            for (int kb = 0; kb < 8; ++kb) {
                const int widx = ((rt * 16 + col) << 8) + (((kb << 5) + (grp << 3)) ^ xk);
                const bf16x8 wf = *(const bf16x8*)&Sg[widx];
                a = __builtin_amdgcn_mfma_f32_16x16x32_bf16(wf, sf[kb], a, 0, 0, 0);
            }
            #pragma unroll
            for (int r = 0; r < 4; ++r)
                up[rt][r] = upre[rt * 4 + r] - a[r];
        }
        // --- write u' (bf16, col-major) to Ub
        #pragma unroll
        for (int rt = 0; rt < 2; ++rt) {
            ushort4 p;
            p.x = f2bf(up[rt][0]); p.y = f2bf(up[rt][1]);
            p.z = f2bf(up[rt][2]); p.w = f2bf(up[rt][3]);
            *(ushort4*)&Ub[col * 40 + rt * 16 + grp * 4] = p;
        }
        const bf16x8 uf = *(const bf16x8*)&Ub[col * 40 + grp * 8];

        // --- o = q@S + aloc@u' ; store to dt
        #pragma unroll
        for (int rt = 0; rt < 2; ++rt) {
            f32x4 a; a[0] = 0.f; a[1] = 0.f; a[2] = 0.f; a[3] = 0.f;
            #pragma unroll
            for (int kb = 0; kb < 8; ++kb) {
                const int qidx = 8192 + ((rt * 16 + col) << 8) + (((kb << 5) + (grp << 3)) ^ xk);
                const bf16x8 qf = *(const bf16x8*)&Sg[qidx];
                a = __builtin_amdgcn_mfma_f32_16x16x32_bf16(qf, sf[kb], a, 0, 0, 0);
            }
            const bf16x8 alf = *(const bf16x8*)&Sg[24576 + rt * 512 + col * 32 + grp * 8];
            a = __builtin_amdgcn_mfma_f32_16x16x32_bf16(alf, uf, a, 0, 0, 0);
            #pragma unroll
            for (int r = 0; r < 4; ++r)
                dp[(long)n * 32768 + rt * 16384 + r * 1024] = a[r];
        }

        // --- S += kT @ u'
        #pragma unroll
        for (int t = 0; t < 16; ++t) {
            const bf16x8 kf = *(const bf16x8*)&Sg[16384 + t * 512 + col * 32 + grp * 8];
            S[t] = __builtin_amdgcn_mfma_f32_16x16x32_bf16(kf, uf, S[t], 0, 0, 0);
        }

        // --- write S (bf16, col-major) to Sb for next chunk
        #pragma unroll
        for (int t = 0; t < 16; ++t) {
            ushort4 p;
            p.x = f2bf(S[t][0]); p.y = f2bf(S[t][1]);
            p.z = f2bf(S[t][2]); p.w = f2bf(S[t][3]);
            *(ushort4*)&Sb[col * 264 + t * 16 + grp * 4] = p;
        }
    }
}

// ---------------------------------------------------------------------------
// Multiscale causal depthwise conv -> bf16 out. Flat-index identity:
// y[(b*2048+l)*3072 + sc*1024 + c]. Thread = (b, c, 8-l window); window
// loaded once, all 3 scales computed from it, fully unrolled.
// Grid = 4096 blocks x 256 threads.
// ---------------------------------------------------------------------------
__global__ __launch_bounds__(256) void ms_conv(const float* __restrict__ v,
    const float* __restrict__ w3, const float* __restrict__ w15,
    const float* __restrict__ w31, ushort* __restrict__ y)
{
    const int bid = blockIdx.x;
    const int b = bid >> 10;
    const int oct = (bid >> 2) & 255;
    const int c = ((bid & 3) << 8) + threadIdx.x;
    const int l0 = oct << 3;
    const float* vb = v + ((long)b * 2048) * 1024 + c;
    ushort* yb = y + ((long)b * 2048) * 3072 + c;

    float win[38];
    #pragma unroll
    for (int t = 0; t < 38; ++t) {
        const int ll = l0 - 30 + t;
        win[t] = (ll >= 0) ? vb[(long)ll * 1024] : 0.f;
    }
    {   // k=31 (sc=2): taps v[l-30..l] = win[j .. j+30]
        float W[31];
        #pragma unroll
        for (int t = 0; t < 31; ++t) W[t] = w31[c * 31 + t];
        #pragma unroll
        for (int j = 0; j < 8; ++j) {
            float s = 0.f;
            #pragma unroll
            for (int t = 0; t < 31; ++t) s += win[j + t] * W[t];
            yb[(long)(l0 + j) * 3072 + 2048] = f2bf(s);
        }
    }
    {   // k=15 (sc=1): taps v[l-14..l] = win[j+16 .. j+30]
        float W[15];
        #pragma unroll
        for (int t = 0; t < 15; ++t) W[t] = w15[c * 15 + t];
        #pragma unroll
        for (int j = 0; j < 8; ++j) {
            float s = 0.f;
            #pragma unroll
            for (int t = 0; t < 15; ++t) s += win[j + 16 + t] * W[t];
            yb[(long)(l0 + j) * 3072 + 1024] = f2bf(s);
        }
    }
    {   // k=3 (sc=0): taps v[l-2..l] = win[j+28 .. j+30]
        float W[3];
        #pragma unroll
        for (int t = 0; t < 3; ++t) W[t] = w3[c * 3 + t];
        #pragma unroll
        for (int j = 0; j < 8; ++j) {
            float s = 0.f;
            #pragma unroll
            for (int t = 0; t < 3; ++t) s += win[j + 28 + t] * W[t];
            yb[(long)(l0 + j) * 3072] = f2bf(s);
        }
    }
}

// ---------------------------------------------------------------------------
// bn features: bn[bl,12] = [mean|ms| | mean|dt| | mean|v|] per head.
// ---------------------------------------------------------------------------
__global__ __launch_bounds__(256) void build_bn(const float* __restrict__ ms,
    const float* __restrict__ dt, const float* __restrict__ v,
    float* __restrict__ bn)
{
    const int bl = blockIdx.x, tid = threadIdx.x;
    const long rb = (long)bl * 1024;
    const int wid = tid >> 6, lane = tid & 63;
    const long base = rb + wid * 256 + lane * 4;
    float* g = bn + (long)bl * 12;
    float4 a;
    float s;
    a = *(const float4*)(ms + base);
    s = fabsf(a.x) + fabsf(a.y) + fabsf(a.z) + fabsf(a.w);
    for (int off = 32; off > 0; off >>= 1) s += __shfl_down(s, off);
    if (lane == 0) g[wid] = s * (1.f / 256.f);
    a = *(const float4*)(dt + base);
    s = fabsf(a.x) + fabsf(a.y) + fabsf(a.z) + fabsf(a.w);
    for (int off = 32; off > 0; off >>= 1) s += __shfl_down(s, off);
    if (lane == 0) g[4 + wid] = s * (1.f / 256.f);
    a = *(const float4*)(v + base);
    s = fabsf(a.x) + fabsf(a.y) + fabsf(a.z) + fabsf(a.w);
    for (int off = 32; off > 0; off >>= 1) s += __shfl_down(s, off);
    if (lane == 0) g[8 + wid] = s * (1.f / 256.f);
}

// ---------------------------------------------------------------------------
// Blend + per-head RMSNorm * o_norm_w -> bf16 out.
// ---------------------------------------------------------------------------
__global__ __launch_bounds__(256) void blend_rms(const float* __restrict__ ms,
    const float* __restrict__ dt, const float* __restrict__ v,
    const float* __restrict__ wts, const float* __restrict__ onw,
    ushort* __restrict__ o)
{
    const int bl = blockIdx.x, tid = threadIdx.x;
    const int wid = tid >> 6, lane = tid & 63;
    const long base = (long)bl * 1024 + wid * 256 + lane * 4;
    const float* wr = wts + (long)bl * 12 + wid * 3;
    const float w0 = wr[0], w1 = wr[1], w2 = wr[2];
    const float4 m = *(const float4*)(ms + base);
    const float4 d = *(const float4*)(dt + base);
    const float4 x = *(const float4*)(v + base);
    float4 ov;
    ov.x = w0 * m.x + w1 * d.x + w2 * x.x;
    ov.y = w0 * m.y + w1 * d.y + w2 * x.y;
    ov.z = w0 * m.z + w1 * d.z + w2 * x.z;
    ov.w = w0 * m.w + w1 * d.w + w2 * x.w;
    float ss = ov.x * ov.x + ov.y * ov.y + ov.z * ov.z + ov.w * ov.w;
    for (int off = 32; off > 0; off >>= 1) ss += __shfl_down(ss, off);
    ss = __shfl(ss, 0);
    const float inv = rsqrtf(ss * (1.f / 256.f) + 1e-5f);
    const float4 nw = *(const float4*)(onw + lane * 4);
    ushort4 ob;
    ob.x = f2bf(ov.x * inv * nw.x); ob.y = f2bf(ov.y * inv * nw.y);
    ob.z = f2bf(ov.z * inv * nw.z); ob.w = f2bf(ov.w * inv * nw.w);
    *(ushort4*)(o + base) = ob;
}

// ---------------------------------------------------------------------------
extern "C" void kernel_launch(void* const* d_in, const int* in_sizes, int n_in,
                              void* d_out, int out_size, void* d_ws, size_t ws_size,
                              hipStream_t stream)
{
    (void)in_sizes; (void)n_in; (void)out_size; (void)ws_size;
    const float* hid   = (const float*)d_in[0];
    const float* Wq    = (const float*)d_in[1];
    const float* Wk    = (const float*)d_in[2];
    const float* Wv    = (const float*)d_in[3];
    const float* Wb    = (const float*)d_in[4];
    const float* cq    = (const float*)d_in[5];
    const float* ck    = (const float*)d_in[6];
    const float* cv    = (const float*)d_in[7];
    const float* w3    = (const float*)d_in[8];
    const float* w15   = (const float*)d_in[9];
    const float* w31   = (const float*)d_in[10];
    const float* kmix  = (const float*)d_in[11];
    const float* cmix  = (const float*)d_in[12];
    const float* fw1   = (const float*)d_in[13];
    const float* fb1   = (const float*)d_in[14];
    const float* fw2   = (const float*)d_in[15];
    const float* fb2   = (const float*)d_in[16];
    const float* onw   = (const float*)d_in[17];
    const float* Wo    = (const float*)d_in[18];
    float* out = (float*)d_out;

    // ---- workspace carve (peak ~195 MiB) ----
    const size_t MiB = 1024 * 1024;
    char* W = (char*)d_ws;
    float*  s0    = (float*)(W);              // qlin -> u(f32) -> yms[lo] -> hdn16
    char*   s1c   = W + 32 * MiB;             // qtmp -> w16|kT16 -> yms[hi] -> msout
    float*  s1    = (float*)s1c;
    float*  s2    = (float*)(W + 64 * MiB);   // vlin -> dt
    char*   s3    = W + 96 * MiB;             // q16|k16 -> mix16|ofin16
    float*  s4    = (float*)(W + 128 * MiB);  // v (long-lived)
    ushort* hid16 = (ushort*)(W + 160 * MiB);
    ushort* WqT   = (ushort*)(W + 176 * MiB);
    ushort* WkT   = WqT   + 1024 * 1024;
    ushort* WvT   = WkT   + 1024 * 1024;
    ushort* cmixT = WvT   + 1024 * 1024;
    ushort* WoT   = cmixT + 1024 * 1024;
    ushort* fw1T  = WoT   + 1024 * 1024;      // [2048][1024]
    ushort* kmixT = fw1T  + 2048 * 1024;      // [256][768]
    float*  beta  = (float*)(W + 191 * MiB);  // 128 KB
    ushort* al16  = (ushort*)(W + 191 * MiB + 128 * 1024);  // 2 MiB
    float*  bnf   = (float*)(W + 193 * MiB + 128 * 1024);   // 384 KB
    float*  wts   = bnf + 98304;                            // 384 KB

    ushort* q16    = (ushort*)s3;
    ushort* k16    = (ushort*)(s3 + 16 * MiB);
    ushort* mix16  = q16;
    ushort* ofin16 = k16;
    ushort* yms16  = (ushort*)s0;             // 48 MiB spans s0+s1
    ushort* hdn16  = (ushort*)s0;
    float*  qlin = s0; float* qtmp = s1;
    float*  u = s0;
    ushort* w16  = (ushort*)s1c;              // 16 MiB
    ushort* kT16 = (ushort*)(s1c + 16 * MiB); // 16 MiB
    float*  dt = s2; float* v = s4; float* msout = s1;

    const dim3 T256(256);
    // 0. casts / weight transposes
    cast_bf16<<<8192, T256, 0, stream>>>(hid, hid16);
    transpose_cast<<<dim3(32, 32), T256, 0, stream>>>(Wq, WqT, 1024, 1024);
    transpose_cast<<<dim3(32, 32), T256, 0, stream>>>(Wk, WkT, 1024, 1024);
    transpose_cast<<<dim3(32, 32), T256, 0, stream>>>(Wv, WvT, 1024, 1024);
    transpose_cast<<<dim3(32, 32), T256, 0, stream>>>(cmix, cmixT, 1024, 1024);
    transpose_cast<<<dim3(32, 32), T256, 0, stream>>>(Wo, WoT, 1024, 1024);
    transpose_cast<<<dim3(64, 32), T256, 0, stream>>>(fw1, fw1T, 1024, 2048);
    transpose_cast<<<dim3(8, 24), T256, 0, stream>>>(kmix, kmixT, 768, 256);
    // 1. q pipeline
    gemm_mfma<0><<<dim3(8, 64), T256, 0, stream>>>(hid16, WqT, nullptr, nullptr, nullptr, qlin, 8192, 1024, 1024);
    conv4_silu<<<32768, T256, 0, stream>>>(qlin, cq, qtmp);
    l2norm_bf16<<<8192, T256, 0, stream>>>(qtmp, q16);
    // 2. k pipeline
    gemm_mfma<0><<<dim3(8, 64), T256, 0, stream>>>(hid16, WkT, nullptr, nullptr, nullptr, qlin, 8192, 1024, 1024);
    conv4_silu<<<32768, T256, 0, stream>>>(qlin, ck, qtmp);
    l2norm_bf16<<<8192, T256, 0, stream>>>(qtmp, k16);
    // 3. v pipeline
    gemm_mfma<0><<<dim3(8, 64), T256, 0, stream>>>(hid16, WvT, nullptr, nullptr, nullptr, qlin, 8192, 1024, 1024);
    conv4_silu<<<32768, T256, 0, stream>>>(qlin, cv, v);
    // 4. beta
    gemm_smallN<4, 0><<<8192, T256, 0, stream>>>(hid, Wb, nullptr, beta, 1024);
    // 5. delta rule: prep + MFMA scan (staged, dbuf, 1 wave/block)
    chunk_prep<<<1024, T256, 0, stream>>>(q16, k16, v, beta, u, w16, kT16, al16);
    delta_scan_mfma<<<256, dim3(64), 0, stream>>>(q16, kT16, w16, u, al16, dt);
    // 6. multiscale conv branch
    ms_conv<<<4096, T256, 0, stream>>>(v, w3, w15, w31, yms16);
    gemm_mfma<1><<<dim3(2, 256), T256, 0, stream>>>(yms16, kmixT, nullptr, nullptr, nullptr, mix16, 32768, 256, 768);
    gemm_mfma<0><<<dim3(8, 64), T256, 0, stream>>>(mix16, cmixT, nullptr, nullptr, nullptr, msout, 8192, 1024, 1024);
    // 7. fusion gate
    build_bn<<<8192, T256, 0, stream>>>(msout, dt, v, bnf);
    gemm_mfma<3><<<dim3(16, 64), T256, 0, stream>>>(hid16, fw1T, fb1, bnf, fw1 + 1024L * 2048, hdn16, 8192, 2048, 1024);
    gemm_smallN<12, 1><<<8192, T256, 0, stream>>>(hdn16, fw2, fb2, wts, 2048);
    // 8. blend + output projection
    blend_rms<<<8192, T256, 0, stream>>>(msout, dt, v, wts, onw, ofin16);
    gemm_mfma<0><<<dim3(8, 64), T256, 0, stream>>>(ofin16, WoT, nullptr, nullptr, nullptr, out, 8192, 1024, 1024);
}